// Round 1
// 417.295 us; speedup vs baseline: 1.0579x; 1.0579x over previous
//
#include <hip/hip_runtime.h>
#include <hip/hip_bf16.h>
#include <cstddef>

#define GN 50000
#define GE 800000
#define GH 4
#define GD 32
#define SLOPE 0.2f
#define LOG2E 1.4426950408889634f

typedef unsigned short ushort_t;
typedef unsigned int uint_t;
using short8 = __attribute__((ext_vector_type(8))) short;
using float4v = __attribute__((ext_vector_type(4))) float;

__device__ __forceinline__ ushort_t f2bf(float f) {
    union { float f; uint_t u; } v; v.f = f;
    uint_t r = v.u + 0x7fff + ((v.u >> 16) & 1);   // RNE
    return (ushort_t)(r >> 16);
}
__device__ __forceinline__ float bflo(uint_t u) { return __uint_as_float(u << 16); }
__device__ __forceinline__ float bfhi(uint_t u) { return __uint_as_float(u & 0xffff0000u); }
__device__ __forceinline__ float bfu(ushort_t u) { return __uint_as_float((uint_t)u << 16); }

// v_cvt_pk_bf16_f32: D[15:0]=bf16(lo), D[31:16]=bf16(hi), RNE — same rounding as f2bf
__device__ __forceinline__ uint_t cvt_pk_bf16(float lo, float hi) {
    uint_t r;
    asm("v_cvt_pk_bf16_f32 %0, %1, %2" : "=v"(r) : "v"(lo), "v"(hi));
    return r;
}

#if __has_builtin(__builtin_amdgcn_exp2f)
#define EXP2F(x) __builtin_amdgcn_exp2f(x)
#else
#define EXP2F(x) exp2f(x)
#endif

// ---------------- CSR build ----------------
__global__ void k_hist(const int* __restrict__ dst, int* __restrict__ deg, int E) {
    int i = blockIdx.x * 256 + threadIdx.x;
    if (i < E) atomicAdd(&deg[dst[i]], 1);
}

__global__ void k_scan1(const int* __restrict__ deg, int* __restrict__ row_ptr,
                        int* __restrict__ partials, int n) {
    __shared__ int s[256];
    int t = threadIdx.x;
    int i = blockIdx.x * 256 + t;
    int v = (i < n) ? deg[i] : 0;
    s[t] = v;
    __syncthreads();
    for (int off = 1; off < 256; off <<= 1) {
        int add = (t >= off) ? s[t - off] : 0;
        __syncthreads();
        s[t] += add;
        __syncthreads();
    }
    if (i < n) row_ptr[i] = s[t] - v;
    if (t == 255) partials[blockIdx.x] = s[255];
}

__global__ void k_scan2(int* __restrict__ partials, int nb) {
    __shared__ int s[256];
    int t = threadIdx.x;
    int v = (t < nb) ? partials[t] : 0;
    s[t] = v;
    __syncthreads();
    for (int off = 1; off < 256; off <<= 1) {
        int add = (t >= off) ? s[t - off] : 0;
        __syncthreads();
        s[t] += add;
        __syncthreads();
    }
    if (t < nb) partials[t] = s[t] - v;
}

__global__ void k_scan3(int* __restrict__ row_ptr, int* __restrict__ wpos,
                        const int* __restrict__ partials, int n, int E) {
    int i = blockIdx.x * 256 + threadIdx.x;
    if (i < n) {
        int rp = row_ptr[i] + partials[i >> 8];
        row_ptr[i] = rp;
        wpos[i] = rp;
        if (i == 0) row_ptr[n] = E;
    }
}

__global__ void k_fill(const int* __restrict__ src, const int* __restrict__ dst,
                       int* __restrict__ wpos, int* __restrict__ csr_src, int E) {
    int i = blockIdx.x * 256 + threadIdx.x;
    if (i < E) {
        int p = atomicAdd(&wpos[dst[i]], 1);
        csr_src[p] = src[i];
    }
}

// ---------------- weight transpose+convert ----------------
__global__ void k_cvt_w(const float* __restrict__ W0, const float* __restrict__ W1,
                        ushort_t* __restrict__ wbt) {
    int t = blockIdx.x * 256 + threadIdx.x;   // 0..32767
    int m = t >> 14;
    int o = t & 16383;
    int n = o >> 7, k = o & 127;
    const float* W = m ? W1 : W0;
    wbt[t] = f2bf(W[k * 128 + n]);
}

// Wout [128][40] f32 -> transposed bf16 hi/lo planes [48][128] (pad classes 40..47 = 0)
__global__ void k_cvt_wout(const float* __restrict__ Wout, ushort_t* __restrict__ wb) {
    int t = blockIdx.x * 256 + threadIdx.x;   // 0..6143
    if (t >= 48 * 128) return;
    int n = t >> 7, k = t & 127;
    float w = (n < 40) ? Wout[k * 40 + n] : 0.f;
    ushort_t h = f2bf(w);
    float r = w - bfu(h);
    wb[t] = h;
    wb[48 * 128 + t] = f2bf(r);
}

// ---- fused el/er epilogue over MFMA accumulator ----
// NOTE: stores el/er pre-scaled by LOG2E so agg can use raw v_exp_f32 (exp2).
// Legal: leaky_relu is positively homogeneous, exp(x) = exp2(LOG2E*x).
__device__ __forceinline__ void lr_epilogue(const float4v acc[2][8],
                                            const float* __restrict__ al,
                                            const float* __restrict__ ar,
                                            float* __restrict__ el,
                                            float* __restrict__ er,
                                            int r0, int quad, int col, int M) {
#pragma unroll
    for (int rt = 0; rt < 2; rt++) {
#pragma unroll
        for (int h = 0; h < 4; h++) {
            float alv0 = al[h * 32 + col], alv1 = al[h * 32 + 16 + col];
            float arv0 = ar[h * 32 + col], arv1 = ar[h * 32 + 16 + col];
            float pl[4], pr[4];
#pragma unroll
            for (int r = 0; r < 4; r++) {
                pl[r] = acc[rt][2 * h][r] * alv0 + acc[rt][2 * h + 1][r] * alv1;
                pr[r] = acc[rt][2 * h][r] * arv0 + acc[rt][2 * h + 1][r] * arv1;
            }
#pragma unroll
            for (int m = 1; m < 16; m <<= 1) {
#pragma unroll
                for (int r = 0; r < 4; r++) {
                    pl[r] += __shfl_xor(pl[r], m, 64);
                    pr[r] += __shfl_xor(pr[r], m, 64);
                }
            }
            if (col == h) {
#pragma unroll
                for (int r = 0; r < 4; r++) {
                    int row = r0 + rt * 16 + quad * 4 + r;
                    if (row < M) el[row * 4 + h] = pl[r] * LOG2E;
                }
            }
            if (col == 8 + h) {
#pragma unroll
                for (int r = 0; r < 4; r++) {
                    int row = r0 + rt * 16 + quad * 4 + r;
                    if (row < M) er[row * 4 + h] = pr[r] * LOG2E;
                }
            }
        }
    }
}

// C-store: pack row pairs with v_cvt_pk_bf16_f32 (halves convert VALU vs manual f2bf)
__device__ __forceinline__ void store_c_bf16(ushort_t* __restrict__ Cb,
                                             const float4v acc[2][8],
                                             int r0, int quad, int col, int M) {
#pragma unroll
    for (int rt = 0; rt < 2; rt++)
#pragma unroll
        for (int nt = 0; nt < 8; nt++) {
            int rb = r0 + rt * 16 + quad * 4;
            int c = nt * 16 + col;
            uint_t p01 = cvt_pk_bf16(acc[rt][nt][0], acc[rt][nt][1]);
            uint_t p23 = cvt_pk_bf16(acc[rt][nt][2], acc[rt][nt][3]);
            if (rb + 0 < M) Cb[(size_t)(rb + 0) * 128 + c] = (ushort_t)p01;
            if (rb + 1 < M) Cb[(size_t)(rb + 1) * 128 + c] = (ushort_t)(p01 >> 16);
            if (rb + 2 < M) Cb[(size_t)(rb + 2) * 128 + c] = (ushort_t)p23;
            if (rb + 3 < M) Cb[(size_t)(rb + 3) * 128 + c] = (ushort_t)(p23 >> 16);
        }
}

// ---------------- MFMA GEMM (fp32 A, layer 1) + fused el/er ----------------
__global__ __launch_bounds__(256) void gemm_mfma32(const float* __restrict__ A0,
                                                   const float* __restrict__ A1,
                                                   const ushort_t* __restrict__ WbT,
                                                   const float* __restrict__ al,
                                                   const float* __restrict__ ar,
                                                   ushort_t* __restrict__ Cb,
                                                   float* __restrict__ el,
                                                   float* __restrict__ er, int M) {
    __shared__ ushort_t Bs[128][136];
    int tid = threadIdx.x;
    for (int i = tid; i < 128 * 16; i += 256) {
        int n = i >> 4;
        int kc = (i & 15) << 3;
        *(short8*)&Bs[n][kc] = *(const short8*)&WbT[n * 128 + kc];
    }
    __syncthreads();
    int wid = tid >> 6, lane = tid & 63;
    int r0 = blockIdx.x * 128 + wid * 32;
    int col = lane & 15, quad = lane >> 4;
    float4v acc[2][8];
#pragma unroll
    for (int rt = 0; rt < 2; rt++)
#pragma unroll
        for (int t = 0; t < 8; t++) acc[rt][t] = (float4v){0.f, 0.f, 0.f, 0.f};
    int ar_[2] = {r0 + col, r0 + 16 + col};
    const float* Ap[2];
#pragma unroll
    for (int rt = 0; rt < 2; rt++) {
        int a = ar_[rt];
        Ap[rt] = (a < M) ? ((a < GN) ? (A0 + (size_t)a * 128)
                                     : (A1 + (size_t)(a - GN) * 128)) : nullptr;
    }
#pragma unroll
    for (int ks = 0; ks < 4; ks++) {
        short8 af[2];
#pragma unroll
        for (int rt = 0; rt < 2; rt++) {
            af[rt] = (short8){};
            if (Ap[rt]) {
                float4 v0 = *(const float4*)&Ap[rt][ks * 32 + quad * 8];
                float4 v1 = *(const float4*)&Ap[rt][ks * 32 + quad * 8 + 4];
                union { short8 s; uint_t u[4]; } cv;
                cv.u[0] = cvt_pk_bf16(v0.x, v0.y);
                cv.u[1] = cvt_pk_bf16(v0.z, v0.w);
                cv.u[2] = cvt_pk_bf16(v1.x, v1.y);
                cv.u[3] = cvt_pk_bf16(v1.z, v1.w);
                af[rt] = cv.s;
            }
        }
#pragma unroll
        for (int nt = 0; nt < 8; nt++) {
            short8 bf = *(const short8*)&Bs[nt * 16 + col][ks * 32 + quad * 8];
            acc[0][nt] = __builtin_amdgcn_mfma_f32_16x16x32_bf16(af[0], bf, acc[0][nt], 0, 0, 0);
            acc[1][nt] = __builtin_amdgcn_mfma_f32_16x16x32_bf16(af[1], bf, acc[1][nt], 0, 0, 0);
        }
    }
    store_c_bf16(Cb, acc, r0, quad, col, M);
    lr_epilogue(acc, al, ar, el, er, r0, quad, col, M);
}

// ---------------- MFMA GEMM (bf16 A, layer 2) + fused el/er ----------------
__global__ __launch_bounds__(256) void gemm_mfma(const ushort_t* __restrict__ A,
                                                 const ushort_t* __restrict__ WbT,
                                                 const float* __restrict__ al,
                                                 const float* __restrict__ ar,
                                                 ushort_t* __restrict__ Cb,
                                                 float* __restrict__ el,
                                                 float* __restrict__ er, int M) {
    __shared__ ushort_t Bs[128][136];
    int tid = threadIdx.x;
    for (int i = tid; i < 128 * 16; i += 256) {
        int n = i >> 4;
        int kc = (i & 15) << 3;
        *(short8*)&Bs[n][kc] = *(const short8*)&WbT[n * 128 + kc];
    }
    __syncthreads();
    int wid = tid >> 6, lane = tid & 63;
    int r0 = blockIdx.x * 128 + wid * 32;
    int col = lane & 15, quad = lane >> 4;
    float4v acc[2][8];
#pragma unroll
    for (int rt = 0; rt < 2; rt++)
#pragma unroll
        for (int t = 0; t < 8; t++) acc[rt][t] = (float4v){0.f, 0.f, 0.f, 0.f};
    int ar_[2] = {r0 + col, r0 + 16 + col};
#pragma unroll
    for (int ks = 0; ks < 4; ks++) {
        short8 af[2];
#pragma unroll
        for (int rt = 0; rt < 2; rt++) {
            af[rt] = (short8){};
            if (ar_[rt] < M) af[rt] = *(const short8*)&A[(size_t)ar_[rt] * 128 + ks * 32 + quad * 8];
        }
#pragma unroll
        for (int nt = 0; nt < 8; nt++) {
            short8 bf = *(const short8*)&Bs[nt * 16 + col][ks * 32 + quad * 8];
            acc[0][nt] = __builtin_amdgcn_mfma_f32_16x16x32_bf16(af[0], bf, acc[0][nt], 0, 0, 0);
            acc[1][nt] = __builtin_amdgcn_mfma_f32_16x16x32_bf16(af[1], bf, acc[1][nt], 0, 0, 0);
        }
    }
    store_c_bf16(Cb, acc, r0, quad, col, M);
    lr_epilogue(acc, al, ar, el, er, r0, quad, col, M);
}

// ---- shared agg gather core: one wave per node, lanes 0-31 path0, 32-63 path1.
// lane q owns dims 4q..4q+3; head=q>>3. el/er pre-scaled by LOG2E -> raw exp2.
// Uniform-base + 32-bit unsigned indices so the compiler emits saddr-form loads
// (cuts the 64-bit per-lane address chains).
__device__ __forceinline__ void agg_core(
    const ushort_t* __restrict__ featb, const float* __restrict__ el, float ern,
    const int* __restrict__ csr_src, int base, int deg, uint_t ebase, uint_t fbase,
    float& v0, float& v1, float& v2, float& v3) {
    float a0 = 0.f, a1 = 0.f, a2 = 0.f, a3 = 0.f, ss = 0.f;
    int i = 0;
    for (; i + 8 <= deg; i += 8) {
        int j = base + i;
        int s0 = csr_src[j + 0], s1 = csr_src[j + 1], s2 = csr_src[j + 2], s3 = csr_src[j + 3];
        int s4 = csr_src[j + 4], s5 = csr_src[j + 5], s6 = csr_src[j + 6], s7 = csr_src[j + 7];
        float e0 = el[ebase + (uint_t)s0 * 4u] + ern;
        float e1 = el[ebase + (uint_t)s1 * 4u] + ern;
        float e2 = el[ebase + (uint_t)s2 * 4u] + ern;
        float e3 = el[ebase + (uint_t)s3 * 4u] + ern;
        float e4 = el[ebase + (uint_t)s4 * 4u] + ern;
        float e5 = el[ebase + (uint_t)s5 * 4u] + ern;
        float e6 = el[ebase + (uint_t)s6 * 4u] + ern;
        float e7 = el[ebase + (uint_t)s7 * 4u] + ern;
        uint2 f0 = *(const uint2*)&featb[fbase + (uint_t)s0 * 128u];
        uint2 f1 = *(const uint2*)&featb[fbase + (uint_t)s1 * 128u];
        uint2 f2 = *(const uint2*)&featb[fbase + (uint_t)s2 * 128u];
        uint2 f3 = *(const uint2*)&featb[fbase + (uint_t)s3 * 128u];
        uint2 f4 = *(const uint2*)&featb[fbase + (uint_t)s4 * 128u];
        uint2 f5 = *(const uint2*)&featb[fbase + (uint_t)s5 * 128u];
        uint2 f6 = *(const uint2*)&featb[fbase + (uint_t)s6 * 128u];
        uint2 f7 = *(const uint2*)&featb[fbase + (uint_t)s7 * 128u];
        e0 = fmaxf(e0, SLOPE * e0);
        e1 = fmaxf(e1, SLOPE * e1);
        e2 = fmaxf(e2, SLOPE * e2);
        e3 = fmaxf(e3, SLOPE * e3);
        e4 = fmaxf(e4, SLOPE * e4);
        e5 = fmaxf(e5, SLOPE * e5);
        e6 = fmaxf(e6, SLOPE * e6);
        e7 = fmaxf(e7, SLOPE * e7);
        float w0 = EXP2F(e0), w1 = EXP2F(e1), w2 = EXP2F(e2), w3 = EXP2F(e3);
        float w4 = EXP2F(e4), w5 = EXP2F(e5), w6 = EXP2F(e6), w7 = EXP2F(e7);
        ss += ((w0 + w1) + (w2 + w3)) + ((w4 + w5) + (w6 + w7));
        a0 += w0 * bflo(f0.x) + w1 * bflo(f1.x) + w2 * bflo(f2.x) + w3 * bflo(f3.x) +
              w4 * bflo(f4.x) + w5 * bflo(f5.x) + w6 * bflo(f6.x) + w7 * bflo(f7.x);
        a1 += w0 * bfhi(f0.x) + w1 * bfhi(f1.x) + w2 * bfhi(f2.x) + w3 * bfhi(f3.x) +
              w4 * bfhi(f4.x) + w5 * bfhi(f5.x) + w6 * bfhi(f6.x) + w7 * bfhi(f7.x);
        a2 += w0 * bflo(f0.y) + w1 * bflo(f1.y) + w2 * bflo(f2.y) + w3 * bflo(f3.y) +
              w4 * bflo(f4.y) + w5 * bflo(f5.y) + w6 * bflo(f6.y) + w7 * bflo(f7.y);
        a3 += w0 * bfhi(f0.y) + w1 * bfhi(f1.y) + w2 * bfhi(f2.y) + w3 * bfhi(f3.y) +
              w4 * bfhi(f4.y) + w5 * bfhi(f5.y) + w6 * bfhi(f6.y) + w7 * bfhi(f7.y);
    }
    for (; i < deg; i++) {
        int j = base + i;
        int s = csr_src[j];
        float e = el[ebase + (uint_t)s * 4u] + ern;
        uint2 f = *(const uint2*)&featb[fbase + (uint_t)s * 128u];
        e = fmaxf(e, SLOPE * e);
        float w = EXP2F(e);
        ss += w;
        a0 += w * bflo(f.x);
        a1 += w * bfhi(f.x);
        a2 += w * bflo(f.y);
        a3 += w * bfhi(f.y);
    }
    float inv = (deg > 0) ? 1.f / ss : 0.f;
    v0 = a0 * inv; v1 = a1 * inv; v2 = a2 * inv; v3 = a3 * inv;
}

// ---------------- layer-1 aggregate: -> abuf (bf16) ----------------
__global__ __launch_bounds__(256) void gat_agg_l1(
    const ushort_t* __restrict__ featb, const float* __restrict__ el,
    const float* __restrict__ er, const int* __restrict__ row_ptr,
    const int* __restrict__ csr_src, ushort_t* __restrict__ abuf) {
    int n = blockIdx.x * 4 + (threadIdx.x >> 6);
    if (n >= GN) return;
    int lane = threadIdx.x & 63;
    int half = lane >> 5;
    int q = lane & 31;
    int head = q >> 3, q4 = q << 2;
    uint_t ebase = (uint_t)(half * (GN * 4) + head);
    uint_t fbase = (uint_t)(half * (GN * 128) + q4);
    float ern = er[ebase + (uint_t)n * 4u];
    int base = row_ptr[n];
    int deg = row_ptr[n + 1] - base;
    float v0, v1, v2, v3;
    agg_core(featb, el, ern, csr_src, base, deg, ebase, fbase, v0, v1, v2, v3);
    v0 = v0 > 0.f ? v0 : __expf(v0) - 1.f;
    v1 = v1 > 0.f ? v1 : __expf(v1) - 1.f;
    v2 = v2 > 0.f ? v2 : __expf(v2) - 1.f;
    v3 = v3 > 0.f ? v3 : __expf(v3) - 1.f;
    size_t idx = ((size_t)n + (size_t)half * GN) * 128 + q4;
    uint2 o;
    o.x = cvt_pk_bf16(v0, v1);
    o.y = cvt_pk_bf16(v2, v3);
    *(uint2*)&abuf[idx] = o;
}

// ---------------- layer-2 aggregate + residual + ELU + mixup + h write ----------------
// (logits moved to dedicated MFMA kernel k_logits; no LDS here -> higher occupancy,
//  no 128-iter 40-lane scalar GEMV tail per wave)
__global__ __launch_bounds__(256) void gat_agg_l2(
    const ushort_t* __restrict__ featb, const float* __restrict__ el,
    const float* __restrict__ er, const int* __restrict__ row_ptr,
    const int* __restrict__ csr_src, const ushort_t* __restrict__ resid,
    const float* __restrict__ lamb, float* __restrict__ outh) {
    int tid = threadIdx.x;
    int n = blockIdx.x * 4 + (tid >> 6);
    if (n >= GN) return;
    int lane = tid & 63;
    int half = lane >> 5;
    int q = lane & 31;
    int head = q >> 3, q4 = q << 2;
    uint_t ebase = (uint_t)(half * (GN * 4) + head);
    uint_t fbase = (uint_t)(half * (GN * 128) + q4);
    float ern = er[ebase + (uint_t)n * 4u];
    int base = row_ptr[n];
    int deg = row_ptr[n + 1] - base;
    float v0, v1, v2, v3;
    agg_core(featb, el, ern, csr_src, base, deg, ebase, fbase, v0, v1, v2, v3);
    // residual (bf16) + ELU
    size_t idx = ((size_t)n + (size_t)half * GN) * 128 + q4;
    ushort4 r = *(const ushort4*)&resid[idx];
    v0 += bfu(r.x); v1 += bfu(r.y); v2 += bfu(r.z); v3 += bfu(r.w);
    v0 = v0 > 0.f ? v0 : __expf(v0) - 1.f;
    v1 = v1 > 0.f ? v1 : __expf(v1) - 1.f;
    v2 = v2 > 0.f ? v2 : __expf(v2) - 1.f;
    v3 = v3 > 0.f ? v3 : __expf(v3) - 1.f;
    // mixup across halves (partner lane = lane ^ 32)
    float p0 = __shfl_xor(v0, 32, 64);
    float p1 = __shfl_xor(v1, 32, 64);
    float p2 = __shfl_xor(v2, 32, 64);
    float p3 = __shfl_xor(v3, 32, 64);
    float lam = lamb[0];
    if (half == 0) {
        float m0 = lam * v0 + (1.f - lam) * p0;
        float m1 = lam * v1 + (1.f - lam) * p1;
        float m2 = lam * v2 + (1.f - lam) * p2;
        float m3 = lam * v3 + (1.f - lam) * p3;
        *(float4*)&outh[(size_t)n * 128 + q4] = make_float4(m0, m1, m2, m3);
    }
}

// ---------------- logits: H[N,128] (f32) x Wout[128,40] via 3-product bf16-split MFMA
// hi*Whi + lo*Whi + hi*Wlo  => ~2^-16 relative error (fp32-equivalent for this scale).
__global__ __launch_bounds__(256) void k_logits(const float* __restrict__ Hf,
                                                const ushort_t* __restrict__ Wb,
                                                const float* __restrict__ bout,
                                                float* __restrict__ outlog) {
    __shared__ ushort_t Bh[48][136];
    __shared__ ushort_t Bl[48][136];
    int tid = threadIdx.x;
    for (int i = tid; i < 48 * 16; i += 256) {
        int n = i >> 4;
        int kc = (i & 15) << 3;
        *(short8*)&Bh[n][kc] = *(const short8*)&Wb[n * 128 + kc];
        *(short8*)&Bl[n][kc] = *(const short8*)&Wb[48 * 128 + n * 128 + kc];
    }
    __syncthreads();
    int wid = tid >> 6, lane = tid & 63;
    int r0 = blockIdx.x * 128 + wid * 32;
    int col = lane & 15, quad = lane >> 4;
    float4v acc[2][3];
#pragma unroll
    for (int rt = 0; rt < 2; rt++)
#pragma unroll
        for (int nt = 0; nt < 3; nt++) acc[rt][nt] = (float4v){0.f, 0.f, 0.f, 0.f};
    int ar_[2] = {r0 + col, r0 + 16 + col};
#pragma unroll
    for (int ks = 0; ks < 4; ks++) {
        short8 ah[2], alo[2];
#pragma unroll
        for (int rt = 0; rt < 2; rt++) {
            ah[rt] = (short8){};
            alo[rt] = (short8){};
            if (ar_[rt] < GN) {
                const float* p = Hf + (size_t)ar_[rt] * 128 + ks * 32 + quad * 8;
                float4 x = *(const float4*)p;
                float4 y = *(const float4*)(p + 4);
                union { short8 s; uint_t u[4]; } ch, cl;
                ch.u[0] = cvt_pk_bf16(x.x, x.y);
                ch.u[1] = cvt_pk_bf16(x.z, x.w);
                ch.u[2] = cvt_pk_bf16(y.x, y.y);
                ch.u[3] = cvt_pk_bf16(y.z, y.w);
                cl.u[0] = cvt_pk_bf16(x.x - bflo(ch.u[0]), x.y - bfhi(ch.u[0]));
                cl.u[1] = cvt_pk_bf16(x.z - bflo(ch.u[1]), x.w - bfhi(ch.u[1]));
                cl.u[2] = cvt_pk_bf16(y.x - bflo(ch.u[2]), y.y - bfhi(ch.u[2]));
                cl.u[3] = cvt_pk_bf16(y.z - bflo(ch.u[3]), y.w - bfhi(ch.u[3]));
                ah[rt] = ch.s;
                alo[rt] = cl.s;
            }
        }
#pragma unroll
        for (int nt = 0; nt < 3; nt++) {
            short8 bh = *(const short8*)&Bh[nt * 16 + col][ks * 32 + quad * 8];
            short8 bl = *(const short8*)&Bl[nt * 16 + col][ks * 32 + quad * 8];
#pragma unroll
            for (int rt = 0; rt < 2; rt++) {
                acc[rt][nt] = __builtin_amdgcn_mfma_f32_16x16x32_bf16(ah[rt], bh, acc[rt][nt], 0, 0, 0);
                acc[rt][nt] = __builtin_amdgcn_mfma_f32_16x16x32_bf16(alo[rt], bh, acc[rt][nt], 0, 0, 0);
                acc[rt][nt] = __builtin_amdgcn_mfma_f32_16x16x32_bf16(ah[rt], bl, acc[rt][nt], 0, 0, 0);
            }
        }
    }
#pragma unroll
    for (int nt = 0; nt < 3; nt++) {
        int c = nt * 16 + col;
        if (c < 40) {
            float bv = bout[c];
#pragma unroll
            for (int rt = 0; rt < 2; rt++)
#pragma unroll
                for (int r = 0; r < 4; r++) {
                    int row = r0 + rt * 16 + quad * 4 + r;
                    if (row < GN) outlog[(size_t)row * 40 + c] = acc[rt][nt][r] + bv;
                }
        }
    }
}

extern "C" void kernel_launch(void* const* d_in, const int* in_sizes, int n_in,
                              void* d_out, int out_size, void* d_ws, size_t ws_size,
                              hipStream_t stream) {
    const float* inputs = (const float*)d_in[0];
    const float* target = (const float*)d_in[1];
    const float* lamb   = (const float*)d_in[2];
    const float* W0     = (const float*)d_in[3];
    const float* al0    = (const float*)d_in[4];
    const float* ar0    = (const float*)d_in[5];
    const float* W1     = (const float*)d_in[6];
    const float* al1    = (const float*)d_in[7];
    const float* ar1    = (const float*)d_in[8];
    const float* Wout   = (const float*)d_in[9];
    const float* bout   = (const float*)d_in[10];
    const int*   src    = (const int*)d_in[11];
    const int*   dst    = (const int*)d_in[12];

    float* out = (float*)d_out;
    float* outh = out;                          // [N,128]
    float* outlog = out + (size_t)GN * 128;     // [N,40]

    const int NP = 2 * GN;
    // workspace layout
    ushort_t* featb = (ushort_t*)d_ws;                    // [2N,128] bf16
    ushort_t* abuf  = featb + (size_t)NP * 128;           // [2N,128] bf16 (layer1 out / resid)
    float* el = (float*)(abuf + (size_t)NP * 128);        // [2N,4]  (pre-scaled by LOG2E)
    float* er = el + (size_t)NP * GH;                     // [2N,4]  (pre-scaled by LOG2E)
    ushort_t* wbt = (ushort_t*)(er + (size_t)NP * GH);    // [2][128][128] bf16
    int* row_ptr  = (int*)(wbt + 2 * 128 * 128);          // N+1
    int* wpos     = row_ptr + (GN + 1);                   // N
    int* csr_src  = wpos + GN;                            // E (+pad)
    int* partials = csr_src + GE + 16;                    // 256
    ushort_t* woutb = (ushort_t*)(partials + 256);        // [2][48][128] bf16 hi/lo

    const int nb = (GN + 255) / 256;
    const int eb = (GE + 255) / 256;
    const int gblocks = (NP + 127) / 128;
    const int aggblocks = (GN + 3) / 4;
    const int lblocks = (GN + 127) / 128;

    // ---- CSR build ----
    hipMemsetAsync(wpos, 0, GN * sizeof(int), stream);
    k_hist<<<eb, 256, 0, stream>>>(dst, wpos, GE);
    k_scan1<<<nb, 256, 0, stream>>>(wpos, row_ptr, partials, GN);
    k_scan2<<<1, 256, 0, stream>>>(partials, nb);
    k_scan3<<<nb, 256, 0, stream>>>(row_ptr, wpos, partials, GN, GE);
    k_fill<<<eb, 256, 0, stream>>>(src, dst, wpos, csr_src, GE);

    // ---- weights convert ----
    k_cvt_w<<<128, 256, 0, stream>>>(W0, W1, wbt);
    k_cvt_wout<<<24, 256, 0, stream>>>(Wout, woutb);

    // ---- layer 1 (GEMM fuses el/er; agg fuses softmax-weight + ELU) ----
    gemm_mfma32<<<gblocks, 256, 0, stream>>>(inputs, target, wbt, al0, ar0,
                                             featb, el, er, NP);
    gat_agg_l1<<<aggblocks, 256, 0, stream>>>(featb, el, er, row_ptr, csr_src, abuf);

    // ---- layer 2 (agg fuses residual + ELU + mixup + h-write) ----
    gemm_mfma<<<gblocks, 256, 0, stream>>>(abuf, wbt + 128 * 128, al1, ar1,
                                           featb, el, er, NP);
    gat_agg_l2<<<aggblocks, 256, 0, stream>>>(featb, el, er, row_ptr, csr_src,
                                              abuf, lamb, outh);

    // ---- logits from outh (fp32-accurate 3-product bf16 split MFMA) ----
    k_logits<<<lblocks, 256, 0, stream>>>(outh, woutb, bout, outlog);
}

// Round 2
// 415.198 us; speedup vs baseline: 1.0633x; 1.0050x over previous
//
#include <hip/hip_runtime.h>
#include <hip/hip_bf16.h>
#include <cstddef>

#define GN 50000
#define GE 800000
#define GH 4
#define GD 32
#define SLOPE 0.2f
#define LOG2E 1.4426950408889634f

typedef unsigned short ushort_t;
typedef unsigned int uint_t;
using short8 = __attribute__((ext_vector_type(8))) short;
using float4v = __attribute__((ext_vector_type(4))) float;

__device__ __forceinline__ ushort_t f2bf(float f) {
    union { float f; uint_t u; } v; v.f = f;
    uint_t r = v.u + 0x7fff + ((v.u >> 16) & 1);   // RNE
    return (ushort_t)(r >> 16);
}
__device__ __forceinline__ float bflo(uint_t u) { return __uint_as_float(u << 16); }
__device__ __forceinline__ float bfhi(uint_t u) { return __uint_as_float(u & 0xffff0000u); }
__device__ __forceinline__ float bfu(ushort_t u) { return __uint_as_float((uint_t)u << 16); }

// v_cvt_pk_bf16_f32: D[15:0]=bf16(lo), D[31:16]=bf16(hi), RNE — same rounding as f2bf
__device__ __forceinline__ uint_t cvt_pk_bf16(float lo, float hi) {
    uint_t r;
    asm("v_cvt_pk_bf16_f32 %0, %1, %2" : "=v"(r) : "v"(lo), "v"(hi));
    return r;
}

#if __has_builtin(__builtin_amdgcn_exp2f)
#define EXP2F(x) __builtin_amdgcn_exp2f(x)
#else
#define EXP2F(x) exp2f(x)
#endif

// broadcast within each 8-lane group (bits 3,4 of sub-lane preserved, bits 0-2 = k)
#define SWZ_B(v, imm) __uint_as_float((uint_t)__builtin_amdgcn_ds_swizzle((int)__float_as_uint(v), (imm)))

// ---------------- CSR build ----------------
__global__ void k_hist(const int* __restrict__ dst, int* __restrict__ deg, int E) {
    int i = blockIdx.x * 256 + threadIdx.x;
    if (i < E) atomicAdd(&deg[dst[i]], 1);
}

__global__ void k_scan1(const int* __restrict__ deg, int* __restrict__ row_ptr,
                        int* __restrict__ partials, int n) {
    __shared__ int s[256];
    int t = threadIdx.x;
    int i = blockIdx.x * 256 + t;
    int v = (i < n) ? deg[i] : 0;
    s[t] = v;
    __syncthreads();
    for (int off = 1; off < 256; off <<= 1) {
        int add = (t >= off) ? s[t - off] : 0;
        __syncthreads();
        s[t] += add;
        __syncthreads();
    }
    if (i < n) row_ptr[i] = s[t] - v;
    if (t == 255) partials[blockIdx.x] = s[255];
}

__global__ void k_scan2(int* __restrict__ partials, int nb) {
    __shared__ int s[256];
    int t = threadIdx.x;
    int v = (t < nb) ? partials[t] : 0;
    s[t] = v;
    __syncthreads();
    for (int off = 1; off < 256; off <<= 1) {
        int add = (t >= off) ? s[t - off] : 0;
        __syncthreads();
        s[t] += add;
        __syncthreads();
    }
    if (t < nb) partials[t] = s[t] - v;
}

__global__ void k_scan3(int* __restrict__ row_ptr, int* __restrict__ wpos,
                        const int* __restrict__ partials, int n, int E) {
    int i = blockIdx.x * 256 + threadIdx.x;
    if (i < n) {
        int rp = row_ptr[i] + partials[i >> 8];
        row_ptr[i] = rp;
        wpos[i] = rp;
        if (i == 0) row_ptr[n] = E;
    }
}

__global__ void k_fill(const int* __restrict__ src, const int* __restrict__ dst,
                       int* __restrict__ wpos, int* __restrict__ csr_src, int E) {
    int i = blockIdx.x * 256 + threadIdx.x;
    if (i < E) {
        int p = atomicAdd(&wpos[dst[i]], 1);
        csr_src[p] = src[i];
    }
}

// ---------------- weight transpose+convert ----------------
__global__ void k_cvt_w(const float* __restrict__ W0, const float* __restrict__ W1,
                        ushort_t* __restrict__ wbt) {
    int t = blockIdx.x * 256 + threadIdx.x;   // 0..32767
    int m = t >> 14;
    int o = t & 16383;
    int n = o >> 7, k = o & 127;
    const float* W = m ? W1 : W0;
    wbt[t] = f2bf(W[k * 128 + n]);
}

// Wout [128][40] f32 -> transposed bf16 hi/lo planes [48][128] (pad classes 40..47 = 0)
__global__ void k_cvt_wout(const float* __restrict__ Wout, ushort_t* __restrict__ wb) {
    int t = blockIdx.x * 256 + threadIdx.x;   // 0..6143
    if (t >= 48 * 128) return;
    int n = t >> 7, k = t & 127;
    float w = (n < 40) ? Wout[k * 40 + n] : 0.f;
    ushort_t h = f2bf(w);
    float r = w - bfu(h);
    wb[t] = h;
    wb[48 * 128 + t] = f2bf(r);
}

// ---- fused el/er epilogue over MFMA accumulator ----
// NOTE: stores el/er pre-scaled by LOG2E so agg can use raw v_exp_f32 (exp2).
// Legal: leaky_relu is positively homogeneous, exp(x) = exp2(LOG2E*x).
__device__ __forceinline__ void lr_epilogue(const float4v acc[2][8],
                                            const float* __restrict__ al,
                                            const float* __restrict__ ar,
                                            float* __restrict__ el,
                                            float* __restrict__ er,
                                            int r0, int quad, int col, int M) {
#pragma unroll
    for (int rt = 0; rt < 2; rt++) {
#pragma unroll
        for (int h = 0; h < 4; h++) {
            float alv0 = al[h * 32 + col], alv1 = al[h * 32 + 16 + col];
            float arv0 = ar[h * 32 + col], arv1 = ar[h * 32 + 16 + col];
            float pl[4], pr[4];
#pragma unroll
            for (int r = 0; r < 4; r++) {
                pl[r] = acc[rt][2 * h][r] * alv0 + acc[rt][2 * h + 1][r] * alv1;
                pr[r] = acc[rt][2 * h][r] * arv0 + acc[rt][2 * h + 1][r] * arv1;
            }
#pragma unroll
            for (int m = 1; m < 16; m <<= 1) {
#pragma unroll
                for (int r = 0; r < 4; r++) {
                    pl[r] += __shfl_xor(pl[r], m, 64);
                    pr[r] += __shfl_xor(pr[r], m, 64);
                }
            }
            if (col == h) {
#pragma unroll
                for (int r = 0; r < 4; r++) {
                    int row = r0 + rt * 16 + quad * 4 + r;
                    if (row < M) el[row * 4 + h] = pl[r] * LOG2E;
                }
            }
            if (col == 8 + h) {
#pragma unroll
                for (int r = 0; r < 4; r++) {
                    int row = r0 + rt * 16 + quad * 4 + r;
                    if (row < M) er[row * 4 + h] = pr[r] * LOG2E;
                }
            }
        }
    }
}

// C-store: pack row pairs with v_cvt_pk_bf16_f32 (halves convert VALU vs manual f2bf)
__device__ __forceinline__ void store_c_bf16(ushort_t* __restrict__ Cb,
                                             const float4v acc[2][8],
                                             int r0, int quad, int col, int M) {
#pragma unroll
    for (int rt = 0; rt < 2; rt++)
#pragma unroll
        for (int nt = 0; nt < 8; nt++) {
            int rb = r0 + rt * 16 + quad * 4;
            int c = nt * 16 + col;
            uint_t p01 = cvt_pk_bf16(acc[rt][nt][0], acc[rt][nt][1]);
            uint_t p23 = cvt_pk_bf16(acc[rt][nt][2], acc[rt][nt][3]);
            if (rb + 0 < M) Cb[(size_t)(rb + 0) * 128 + c] = (ushort_t)p01;
            if (rb + 1 < M) Cb[(size_t)(rb + 1) * 128 + c] = (ushort_t)(p01 >> 16);
            if (rb + 2 < M) Cb[(size_t)(rb + 2) * 128 + c] = (ushort_t)p23;
            if (rb + 3 < M) Cb[(size_t)(rb + 3) * 128 + c] = (ushort_t)(p23 >> 16);
        }
}

// ---------------- MFMA GEMM (fp32 A, layer 1) + fused el/er ----------------
__global__ __launch_bounds__(256) void gemm_mfma32(const float* __restrict__ A0,
                                                   const float* __restrict__ A1,
                                                   const ushort_t* __restrict__ WbT,
                                                   const float* __restrict__ al,
                                                   const float* __restrict__ ar,
                                                   ushort_t* __restrict__ Cb,
                                                   float* __restrict__ el,
                                                   float* __restrict__ er, int M) {
    __shared__ ushort_t Bs[128][136];
    int tid = threadIdx.x;
    for (int i = tid; i < 128 * 16; i += 256) {
        int n = i >> 4;
        int kc = (i & 15) << 3;
        *(short8*)&Bs[n][kc] = *(const short8*)&WbT[n * 128 + kc];
    }
    __syncthreads();
    int wid = tid >> 6, lane = tid & 63;
    int r0 = blockIdx.x * 128 + wid * 32;
    int col = lane & 15, quad = lane >> 4;
    float4v acc[2][8];
#pragma unroll
    for (int rt = 0; rt < 2; rt++)
#pragma unroll
        for (int t = 0; t < 8; t++) acc[rt][t] = (float4v){0.f, 0.f, 0.f, 0.f};
    int ar_[2] = {r0 + col, r0 + 16 + col};
    const float* Ap[2];
#pragma unroll
    for (int rt = 0; rt < 2; rt++) {
        int a = ar_[rt];
        Ap[rt] = (a < M) ? ((a < GN) ? (A0 + (size_t)a * 128)
                                     : (A1 + (size_t)(a - GN) * 128)) : nullptr;
    }
#pragma unroll
    for (int ks = 0; ks < 4; ks++) {
        short8 af[2];
#pragma unroll
        for (int rt = 0; rt < 2; rt++) {
            af[rt] = (short8){};
            if (Ap[rt]) {
                float4 v0 = *(const float4*)&Ap[rt][ks * 32 + quad * 8];
                float4 v1 = *(const float4*)&Ap[rt][ks * 32 + quad * 8 + 4];
                union { short8 s; uint_t u[4]; } cv;
                cv.u[0] = cvt_pk_bf16(v0.x, v0.y);
                cv.u[1] = cvt_pk_bf16(v0.z, v0.w);
                cv.u[2] = cvt_pk_bf16(v1.x, v1.y);
                cv.u[3] = cvt_pk_bf16(v1.z, v1.w);
                af[rt] = cv.s;
            }
        }
#pragma unroll
        for (int nt = 0; nt < 8; nt++) {
            short8 bf = *(const short8*)&Bs[nt * 16 + col][ks * 32 + quad * 8];
            acc[0][nt] = __builtin_amdgcn_mfma_f32_16x16x32_bf16(af[0], bf, acc[0][nt], 0, 0, 0);
            acc[1][nt] = __builtin_amdgcn_mfma_f32_16x16x32_bf16(af[1], bf, acc[1][nt], 0, 0, 0);
        }
    }
    store_c_bf16(Cb, acc, r0, quad, col, M);
    lr_epilogue(acc, al, ar, el, er, r0, quad, col, M);
}

// ---------------- MFMA GEMM (bf16 A, layer 2) + fused el/er ----------------
__global__ __launch_bounds__(256) void gemm_mfma(const ushort_t* __restrict__ A,
                                                 const ushort_t* __restrict__ WbT,
                                                 const float* __restrict__ al,
                                                 const float* __restrict__ ar,
                                                 ushort_t* __restrict__ Cb,
                                                 float* __restrict__ el,
                                                 float* __restrict__ er, int M) {
    __shared__ ushort_t Bs[128][136];
    int tid = threadIdx.x;
    for (int i = tid; i < 128 * 16; i += 256) {
        int n = i >> 4;
        int kc = (i & 15) << 3;
        *(short8*)&Bs[n][kc] = *(const short8*)&WbT[n * 128 + kc];
    }
    __syncthreads();
    int wid = tid >> 6, lane = tid & 63;
    int r0 = blockIdx.x * 128 + wid * 32;
    int col = lane & 15, quad = lane >> 4;
    float4v acc[2][8];
#pragma unroll
    for (int rt = 0; rt < 2; rt++)
#pragma unroll
        for (int t = 0; t < 8; t++) acc[rt][t] = (float4v){0.f, 0.f, 0.f, 0.f};
    int ar_[2] = {r0 + col, r0 + 16 + col};
#pragma unroll
    for (int ks = 0; ks < 4; ks++) {
        short8 af[2];
#pragma unroll
        for (int rt = 0; rt < 2; rt++) {
            af[rt] = (short8){};
            if (ar_[rt] < M) af[rt] = *(const short8*)&A[(size_t)ar_[rt] * 128 + ks * 32 + quad * 8];
        }
#pragma unroll
        for (int nt = 0; nt < 8; nt++) {
            short8 bf = *(const short8*)&Bs[nt * 16 + col][ks * 32 + quad * 8];
            acc[0][nt] = __builtin_amdgcn_mfma_f32_16x16x32_bf16(af[0], bf, acc[0][nt], 0, 0, 0);
            acc[1][nt] = __builtin_amdgcn_mfma_f32_16x16x32_bf16(af[1], bf, acc[1][nt], 0, 0, 0);
        }
    }
    store_c_bf16(Cb, acc, r0, quad, col, M);
    lr_epilogue(acc, al, ar, el, er, r0, quad, col, M);
}

// ---- shared agg gather core: one wave per node, lanes 0-31 path0, 32-63 path1.
// lane q owns dims 4q..4q+3; head=q>>3. el/er pre-scaled by LOG2E -> raw exp2.
//
// This version:
//  * n/base/deg/csr indices are wave-uniform (rooted in readfirstlane) -> the
//    compiler keeps them in SGPRs, csr reads become s_load (scalar pipe,
//    lgkmcnt — overlaps the vector gathers), and each feature-row base is a
//    UNIFORM pointer so gathers are saddr-form with a per-lane-constant voffset.
//  * weight compute deduplicated 8x: lane l computes exp2 for edge (l&7) of
//    its own (head,half); the 8-lane group shares via ds_swizzle broadcasts.
//    Bitwise-identical values to the replicated version.
//  * software pipeline: next iteration's csr indices are fetched while the
//    current iteration's feature gathers are in flight (halves the serial
//    memory round-trips per node).
__device__ __forceinline__ void agg_core(
    const ushort_t* __restrict__ featb, const float* __restrict__ el, float ern,
    const int* __restrict__ csr_src, int base, int deg, uint_t ebase, uint_t fofs,
    int lane, float& v0, float& v1, float& v2, float& v3) {
    float a0 = 0.f, a1 = 0.f, a2 = 0.f, a3 = 0.f, ss = 0.f;
    int nmain = deg & ~7;
    int lk = lane & 7;
    if (nmain) {
        int jb = base;
        int s0 = csr_src[jb + 0], s1 = csr_src[jb + 1], s2 = csr_src[jb + 2], s3 = csr_src[jb + 3];
        int s4 = csr_src[jb + 4], s5 = csr_src[jb + 5], s6 = csr_src[jb + 6], s7 = csr_src[jb + 7];
        int sown = csr_src[jb + lk];
        int i = 0;
        for (;;) {
            // feature gathers (uniform row base + per-lane voffset)
            const ushort_t* p0 = featb + (uint_t)s0 * 128u;
            const ushort_t* p1 = featb + (uint_t)s1 * 128u;
            const ushort_t* p2 = featb + (uint_t)s2 * 128u;
            const ushort_t* p3 = featb + (uint_t)s3 * 128u;
            const ushort_t* p4 = featb + (uint_t)s4 * 128u;
            const ushort_t* p5 = featb + (uint_t)s5 * 128u;
            const ushort_t* p6 = featb + (uint_t)s6 * 128u;
            const ushort_t* p7 = featb + (uint_t)s7 * 128u;
            uint2 f0 = *(const uint2*)&p0[fofs];
            uint2 f1 = *(const uint2*)&p1[fofs];
            uint2 f2 = *(const uint2*)&p2[fofs];
            uint2 f3 = *(const uint2*)&p3[fofs];
            uint2 f4 = *(const uint2*)&p4[fofs];
            uint2 f5 = *(const uint2*)&p5[fofs];
            uint2 f6 = *(const uint2*)&p6[fofs];
            uint2 f7 = *(const uint2*)&p7[fofs];
            // this lane's weight edge (l&7)
            float e = el[ebase + (uint_t)sown * 4u] + ern;
            // prefetch next block's csr indices while gathers are in flight
            bool more = (i + 8) < nmain;
            int t0 = 0, t1 = 0, t2 = 0, t3 = 0, t4 = 0, t5 = 0, t6 = 0, t7 = 0, town = 0;
            if (more) {
                int nj = jb + 8;
                t0 = csr_src[nj + 0]; t1 = csr_src[nj + 1]; t2 = csr_src[nj + 2]; t3 = csr_src[nj + 3];
                t4 = csr_src[nj + 4]; t5 = csr_src[nj + 5]; t6 = csr_src[nj + 6]; t7 = csr_src[nj + 7];
                town = csr_src[nj + lk];
            }
            e = fmaxf(e, SLOPE * e);
            float wown = EXP2F(e);
            // broadcast the 8 weights across the 8-lane (head,half) group
            float w0 = SWZ_B(wown, 0x018);
            float w1 = SWZ_B(wown, 0x038);
            float w2 = SWZ_B(wown, 0x058);
            float w3 = SWZ_B(wown, 0x078);
            float w4 = SWZ_B(wown, 0x098);
            float w5 = SWZ_B(wown, 0x0B8);
            float w6 = SWZ_B(wown, 0x0D8);
            float w7 = SWZ_B(wown, 0x0F8);
            ss += ((w0 + w1) + (w2 + w3)) + ((w4 + w5) + (w6 + w7));
            a0 += w0 * bflo(f0.x) + w1 * bflo(f1.x) + w2 * bflo(f2.x) + w3 * bflo(f3.x) +
                  w4 * bflo(f4.x) + w5 * bflo(f5.x) + w6 * bflo(f6.x) + w7 * bflo(f7.x);
            a1 += w0 * bfhi(f0.x) + w1 * bfhi(f1.x) + w2 * bfhi(f2.x) + w3 * bfhi(f3.x) +
                  w4 * bfhi(f4.x) + w5 * bfhi(f5.x) + w6 * bfhi(f6.x) + w7 * bfhi(f7.x);
            a2 += w0 * bflo(f0.y) + w1 * bflo(f1.y) + w2 * bflo(f2.y) + w3 * bflo(f3.y) +
                  w4 * bflo(f4.y) + w5 * bflo(f5.y) + w6 * bflo(f6.y) + w7 * bflo(f7.y);
            a3 += w0 * bfhi(f0.y) + w1 * bfhi(f1.y) + w2 * bfhi(f2.y) + w3 * bfhi(f3.y) +
                  w4 * bfhi(f4.y) + w5 * bfhi(f5.y) + w6 * bfhi(f6.y) + w7 * bfhi(f7.y);
            if (!more) break;
            i += 8; jb += 8;
            s0 = t0; s1 = t1; s2 = t2; s3 = t3; s4 = t4; s5 = t5; s6 = t6; s7 = t7;
            sown = town;
        }
    }
    for (int i = nmain; i < deg; i++) {
        int s = csr_src[base + i];
        float e = el[ebase + (uint_t)s * 4u] + ern;
        const ushort_t* p = featb + (uint_t)s * 128u;
        uint2 f = *(const uint2*)&p[fofs];
        e = fmaxf(e, SLOPE * e);
        float w = EXP2F(e);
        ss += w;
        a0 += w * bflo(f.x);
        a1 += w * bfhi(f.x);
        a2 += w * bflo(f.y);
        a3 += w * bfhi(f.y);
    }
    float inv = (deg > 0) ? 1.f / ss : 0.f;
    v0 = a0 * inv; v1 = a1 * inv; v2 = a2 * inv; v3 = a3 * inv;
}

// ---------------- layer-1 aggregate: -> abuf (bf16) ----------------
__global__ __launch_bounds__(256) void gat_agg_l1(
    const ushort_t* __restrict__ featb, const float* __restrict__ el,
    const float* __restrict__ er, const int* __restrict__ row_ptr,
    const int* __restrict__ csr_src, ushort_t* __restrict__ abuf) {
    int n = __builtin_amdgcn_readfirstlane(blockIdx.x * 4 + (threadIdx.x >> 6));
    if (n >= GN) return;
    int lane = threadIdx.x & 63;
    int half = lane >> 5;
    int q = lane & 31;
    int head = (lane >> 3) & 3, q4 = q << 2;
    uint_t ebase = (uint_t)(half * (GN * 4) + head);
    uint_t fofs = (uint_t)(half * (GN * 128) + q4);
    float ern = er[ebase + (uint_t)n * 4u];
    int base = row_ptr[n];
    int deg = row_ptr[n + 1] - base;
    float v0, v1, v2, v3;
    agg_core(featb, el, ern, csr_src, base, deg, ebase, fofs, lane, v0, v1, v2, v3);
    v0 = v0 > 0.f ? v0 : __expf(v0) - 1.f;
    v1 = v1 > 0.f ? v1 : __expf(v1) - 1.f;
    v2 = v2 > 0.f ? v2 : __expf(v2) - 1.f;
    v3 = v3 > 0.f ? v3 : __expf(v3) - 1.f;
    size_t idx = ((size_t)n + (size_t)half * GN) * 128 + q4;
    uint2 o;
    o.x = cvt_pk_bf16(v0, v1);
    o.y = cvt_pk_bf16(v2, v3);
    *(uint2*)&abuf[idx] = o;
}

// ---------------- layer-2 aggregate + residual + ELU + mixup + h write ----------------
__global__ __launch_bounds__(256) void gat_agg_l2(
    const ushort_t* __restrict__ featb, const float* __restrict__ el,
    const float* __restrict__ er, const int* __restrict__ row_ptr,
    const int* __restrict__ csr_src, const ushort_t* __restrict__ resid,
    const float* __restrict__ lamb, float* __restrict__ outh) {
    int tid = threadIdx.x;
    int n = __builtin_amdgcn_readfirstlane(blockIdx.x * 4 + (tid >> 6));
    if (n >= GN) return;
    int lane = tid & 63;
    int half = lane >> 5;
    int q = lane & 31;
    int head = (lane >> 3) & 3, q4 = q << 2;
    uint_t ebase = (uint_t)(half * (GN * 4) + head);
    uint_t fofs = (uint_t)(half * (GN * 128) + q4);
    float ern = er[ebase + (uint_t)n * 4u];
    int base = row_ptr[n];
    int deg = row_ptr[n + 1] - base;
    float v0, v1, v2, v3;
    agg_core(featb, el, ern, csr_src, base, deg, ebase, fofs, lane, v0, v1, v2, v3);
    // residual (bf16) + ELU
    size_t idx = ((size_t)n + (size_t)half * GN) * 128 + q4;
    ushort4 r = *(const ushort4*)&resid[idx];
    v0 += bfu(r.x); v1 += bfu(r.y); v2 += bfu(r.z); v3 += bfu(r.w);
    v0 = v0 > 0.f ? v0 : __expf(v0) - 1.f;
    v1 = v1 > 0.f ? v1 : __expf(v1) - 1.f;
    v2 = v2 > 0.f ? v2 : __expf(v2) - 1.f;
    v3 = v3 > 0.f ? v3 : __expf(v3) - 1.f;
    // mixup across halves (partner lane = lane ^ 32)
    float p0 = __shfl_xor(v0, 32, 64);
    float p1 = __shfl_xor(v1, 32, 64);
    float p2 = __shfl_xor(v2, 32, 64);
    float p3 = __shfl_xor(v3, 32, 64);
    float lam = lamb[0];
    if (half == 0) {
        float m0 = lam * v0 + (1.f - lam) * p0;
        float m1 = lam * v1 + (1.f - lam) * p1;
        float m2 = lam * v2 + (1.f - lam) * p2;
        float m3 = lam * v3 + (1.f - lam) * p3;
        *(float4*)&outh[(size_t)n * 128 + q4] = make_float4(m0, m1, m2, m3);
    }
}

// ---------------- logits: H[N,128] (f32) x Wout[128,40] via 3-product bf16-split MFMA
// hi*Whi + lo*Whi + hi*Wlo  => ~2^-16 relative error (fp32-equivalent for this scale).
__global__ __launch_bounds__(256) void k_logits(const float* __restrict__ Hf,
                                                const ushort_t* __restrict__ Wb,
                                                const float* __restrict__ bout,
                                                float* __restrict__ outlog) {
    __shared__ ushort_t Bh[48][136];
    __shared__ ushort_t Bl[48][136];
    int tid = threadIdx.x;
    for (int i = tid; i < 48 * 16; i += 256) {
        int n = i >> 4;
        int kc = (i & 15) << 3;
        *(short8*)&Bh[n][kc] = *(const short8*)&Wb[n * 128 + kc];
        *(short8*)&Bl[n][kc] = *(const short8*)&Wb[48 * 128 + n * 128 + kc];
    }
    __syncthreads();
    int wid = tid >> 6, lane = tid & 63;
    int r0 = blockIdx.x * 128 + wid * 32;
    int col = lane & 15, quad = lane >> 4;
    float4v acc[2][3];
#pragma unroll
    for (int rt = 0; rt < 2; rt++)
#pragma unroll
        for (int nt = 0; nt < 3; nt++) acc[rt][nt] = (float4v){0.f, 0.f, 0.f, 0.f};
    int ar_[2] = {r0 + col, r0 + 16 + col};
#pragma unroll
    for (int ks = 0; ks < 4; ks++) {
        short8 ah[2], alo[2];
#pragma unroll
        for (int rt = 0; rt < 2; rt++) {
            ah[rt] = (short8){};
            alo[rt] = (short8){};
            if (ar_[rt] < GN) {
                const float* p = Hf + (size_t)ar_[rt] * 128 + ks * 32 + quad * 8;
                float4 x = *(const float4*)p;
                float4 y = *(const float4*)(p + 4);
                union { short8 s; uint_t u[4]; } ch, cl;
                ch.u[0] = cvt_pk_bf16(x.x, x.y);
                ch.u[1] = cvt_pk_bf16(x.z, x.w);
                ch.u[2] = cvt_pk_bf16(y.x, y.y);
                ch.u[3] = cvt_pk_bf16(y.z, y.w);
                cl.u[0] = cvt_pk_bf16(x.x - bflo(ch.u[0]), x.y - bfhi(ch.u[0]));
                cl.u[1] = cvt_pk_bf16(x.z - bflo(ch.u[1]), x.w - bfhi(ch.u[1]));
                cl.u[2] = cvt_pk_bf16(y.x - bflo(ch.u[2]), y.y - bfhi(ch.u[2]));
                cl.u[3] = cvt_pk_bf16(y.z - bflo(ch.u[3]), y.w - bfhi(ch.u[3]));
                ah[rt] = ch.s;
                alo[rt] = cl.s;
            }
        }
#pragma unroll
        for (int nt = 0; nt < 3; nt++) {
            short8 bh = *(const short8*)&Bh[nt * 16 + col][ks * 32 + quad * 8];
            short8 bl = *(const short8*)&Bl[nt * 16 + col][ks * 32 + quad * 8];
#pragma unroll
            for (int rt = 0; rt < 2; rt++) {
                acc[rt][nt] = __builtin_amdgcn_mfma_f32_16x16x32_bf16(ah[rt], bh, acc[rt][nt], 0, 0, 0);
                acc[rt][nt] = __builtin_amdgcn_mfma_f32_16x16x32_bf16(alo[rt], bh, acc[rt][nt], 0, 0, 0);
                acc[rt][nt] = __builtin_amdgcn_mfma_f32_16x16x32_bf16(ah[rt], bl, acc[rt][nt], 0, 0, 0);
            }
        }
    }
#pragma unroll
    for (int nt = 0; nt < 3; nt++) {
        int c = nt * 16 + col;
        if (c < 40) {
            float bv = bout[c];
#pragma unroll
            for (int rt = 0; rt < 2; rt++)
#pragma unroll
                for (int r = 0; r < 4; r++) {
                    int row = r0 + rt * 16 + quad * 4 + r;
                    if (row < GN) outlog[(size_t)row * 40 + c] = acc[rt][nt][r] + bv;
                }
        }
    }
}

extern "C" void kernel_launch(void* const* d_in, const int* in_sizes, int n_in,
                              void* d_out, int out_size, void* d_ws, size_t ws_size,
                              hipStream_t stream) {
    const float* inputs = (const float*)d_in[0];
    const float* target = (const float*)d_in[1];
    const float* lamb   = (const float*)d_in[2];
    const float* W0     = (const float*)d_in[3];
    const float* al0    = (const float*)d_in[4];
    const float* ar0    = (const float*)d_in[5];
    const float* W1     = (const float*)d_in[6];
    const float* al1    = (const float*)d_in[7];
    const float* ar1    = (const float*)d_in[8];
    const float* Wout   = (const float*)d_in[9];
    const float* bout   = (const float*)d_in[10];
    const int*   src    = (const int*)d_in[11];
    const int*   dst    = (const int*)d_in[12];

    float* out = (float*)d_out;
    float* outh = out;                          // [N,128]
    float* outlog = out + (size_t)GN * 128;     // [N,40]

    const int NP = 2 * GN;
    // workspace layout
    ushort_t* featb = (ushort_t*)d_ws;                    // [2N,128] bf16
    ushort_t* abuf  = featb + (size_t)NP * 128;           // [2N,128] bf16 (layer1 out / resid)
    float* el = (float*)(abuf + (size_t)NP * 128);        // [2N,4]  (pre-scaled by LOG2E)
    float* er = el + (size_t)NP * GH;                     // [2N,4]  (pre-scaled by LOG2E)
    ushort_t* wbt = (ushort_t*)(er + (size_t)NP * GH);    // [2][128][128] bf16
    int* row_ptr  = (int*)(wbt + 2 * 128 * 128);          // N+1
    int* wpos     = row_ptr + (GN + 1);                   // N
    int* csr_src  = wpos + GN;                            // E (+pad)
    int* partials = csr_src + GE + 16;                    // 256
    ushort_t* woutb = (ushort_t*)(partials + 256);        // [2][48][128] bf16 hi/lo

    const int nb = (GN + 255) / 256;
    const int eb = (GE + 255) / 256;
    const int gblocks = (NP + 127) / 128;
    const int aggblocks = (GN + 3) / 4;
    const int lblocks = (GN + 127) / 128;

    // ---- CSR build ----
    hipMemsetAsync(wpos, 0, GN * sizeof(int), stream);
    k_hist<<<eb, 256, 0, stream>>>(dst, wpos, GE);
    k_scan1<<<nb, 256, 0, stream>>>(wpos, row_ptr, partials, GN);
    k_scan2<<<1, 256, 0, stream>>>(partials, nb);
    k_scan3<<<nb, 256, 0, stream>>>(row_ptr, wpos, partials, GN, GE);
    k_fill<<<eb, 256, 0, stream>>>(src, dst, wpos, csr_src, GE);

    // ---- weights convert ----
    k_cvt_w<<<128, 256, 0, stream>>>(W0, W1, wbt);
    k_cvt_wout<<<24, 256, 0, stream>>>(Wout, woutb);

    // ---- layer 1 (GEMM fuses el/er; agg fuses softmax-weight + ELU) ----
    gemm_mfma32<<<gblocks, 256, 0, stream>>>(inputs, target, wbt, al0, ar0,
                                             featb, el, er, NP);
    gat_agg_l1<<<aggblocks, 256, 0, stream>>>(featb, el, er, row_ptr, csr_src, abuf);

    // ---- layer 2 (agg fuses residual + ELU + mixup + h-write) ----
    gemm_mfma<<<gblocks, 256, 0, stream>>>(abuf, wbt + 128 * 128, al1, ar1,
                                           featb, el, er, NP);
    gat_agg_l2<<<aggblocks, 256, 0, stream>>>(featb, el, er, row_ptr, csr_src,
                                              abuf, lamb, outh);

    // ---- logits from outh (fp32-accurate 3-product bf16 split MFMA) ----
    k_logits<<<lblocks, 256, 0, stream>>>(outh, woutb, bout, outlog);
}

// Round 3
// 406.795 us; speedup vs baseline: 1.0852x; 1.0207x over previous
//
#include <hip/hip_runtime.h>
#include <hip/hip_bf16.h>
#include <cstddef>

#define GN 50000
#define GE 800000
#define GH 4
#define GD 32
#define SLOPE 0.2f
#define LOG2E 1.4426950408889634f

typedef unsigned short ushort_t;
typedef unsigned int uint_t;
using short8 = __attribute__((ext_vector_type(8))) short;
using float4v = __attribute__((ext_vector_type(4))) float;

__device__ __forceinline__ ushort_t f2bf(float f) {
    union { float f; uint_t u; } v; v.f = f;
    uint_t r = v.u + 0x7fff + ((v.u >> 16) & 1);   // RNE
    return (ushort_t)(r >> 16);
}
__device__ __forceinline__ float bflo(uint_t u) { return __uint_as_float(u << 16); }
__device__ __forceinline__ float bfhi(uint_t u) { return __uint_as_float(u & 0xffff0000u); }
__device__ __forceinline__ float bfu(ushort_t u) { return __uint_as_float((uint_t)u << 16); }

// v_cvt_pk_bf16_f32: D[15:0]=bf16(lo), D[31:16]=bf16(hi), RNE — same rounding as f2bf
__device__ __forceinline__ uint_t cvt_pk_bf16(float lo, float hi) {
    uint_t r;
    asm("v_cvt_pk_bf16_f32 %0, %1, %2" : "=v"(r) : "v"(lo), "v"(hi));
    return r;
}

#if __has_builtin(__builtin_amdgcn_exp2f)
#define EXP2F(x) __builtin_amdgcn_exp2f(x)
#else
#define EXP2F(x) exp2f(x)
#endif

// broadcast within each 8-lane group (and_mask=0x18 keeps bits 3,4; or_mask=k)
#define SWZ_B(v, imm) __uint_as_float((uint_t)__builtin_amdgcn_ds_swizzle((int)__float_as_uint(v), (imm)))

// path-interleaved row slot: storage row a (0..2N) -> slot (path0/path1 interleaved)
__device__ __forceinline__ int slotmap(int a) {
    return (a < GN) ? (a << 1) : (((a - GN) << 1) | 1);
}

// ---------------- CSR build ----------------
__global__ void k_hist(const int* __restrict__ dst, int* __restrict__ deg, int E) {
    int i = blockIdx.x * 256 + threadIdx.x;
    if (i < E) atomicAdd(&deg[dst[i]], 1);
}

__global__ void k_scan1(const int* __restrict__ deg, int* __restrict__ row_ptr,
                        int* __restrict__ partials, int n) {
    __shared__ int s[256];
    int t = threadIdx.x;
    int i = blockIdx.x * 256 + t;
    int v = (i < n) ? deg[i] : 0;
    s[t] = v;
    __syncthreads();
    for (int off = 1; off < 256; off <<= 1) {
        int add = (t >= off) ? s[t - off] : 0;
        __syncthreads();
        s[t] += add;
        __syncthreads();
    }
    if (i < n) row_ptr[i] = s[t] - v;
    if (t == 255) partials[blockIdx.x] = s[255];
}

__global__ void k_scan2(int* __restrict__ partials, int nb) {
    __shared__ int s[256];
    int t = threadIdx.x;
    int v = (t < nb) ? partials[t] : 0;
    s[t] = v;
    __syncthreads();
    for (int off = 1; off < 256; off <<= 1) {
        int add = (t >= off) ? s[t - off] : 0;
        __syncthreads();
        s[t] += add;
        __syncthreads();
    }
    if (t < nb) partials[t] = s[t] - v;
}

__global__ void k_scan3(int* __restrict__ row_ptr, int* __restrict__ wpos,
                        const int* __restrict__ partials, int n, int E) {
    int i = blockIdx.x * 256 + threadIdx.x;
    if (i < n) {
        int rp = row_ptr[i] + partials[i >> 8];
        row_ptr[i] = rp;
        wpos[i] = rp;
        if (i == 0) row_ptr[n] = E;
    }
}

__global__ void k_fill(const int* __restrict__ src, const int* __restrict__ dst,
                       int* __restrict__ wpos, int* __restrict__ csr_src, int E) {
    int i = blockIdx.x * 256 + threadIdx.x;
    if (i < E) {
        int p = atomicAdd(&wpos[dst[i]], 1);
        csr_src[p] = src[i];
    }
}

// ---------------- weight transpose+convert ----------------
__global__ void k_cvt_w(const float* __restrict__ W0, const float* __restrict__ W1,
                        ushort_t* __restrict__ wbt) {
    int t = blockIdx.x * 256 + threadIdx.x;   // 0..32767
    int m = t >> 14;
    int o = t & 16383;
    int n = o >> 7, k = o & 127;
    const float* W = m ? W1 : W0;
    wbt[t] = f2bf(W[k * 128 + n]);
}

// Wout [128][40] f32 -> transposed bf16 hi/lo planes [48][128] (pad classes 40..47 = 0)
__global__ void k_cvt_wout(const float* __restrict__ Wout, ushort_t* __restrict__ wb) {
    int t = blockIdx.x * 256 + threadIdx.x;   // 0..6143
    if (t >= 48 * 128) return;
    int n = t >> 7, k = t & 127;
    float w = (n < 40) ? Wout[k * 40 + n] : 0.f;
    ushort_t h = f2bf(w);
    float r = w - bfu(h);
    wb[t] = h;
    wb[48 * 128 + t] = f2bf(r);
}

// ---- fused el/er epilogue over MFMA accumulator (interleaved el/er layout) ----
// stores el/er pre-scaled by LOG2E so agg can use raw v_exp_f32 (exp2).
__device__ __forceinline__ void lr_epilogue(const float4v acc[2][8],
                                            const float* __restrict__ al,
                                            const float* __restrict__ ar,
                                            float* __restrict__ el,
                                            float* __restrict__ er,
                                            int r0, int quad, int col, int M) {
#pragma unroll
    for (int rt = 0; rt < 2; rt++) {
#pragma unroll
        for (int h = 0; h < 4; h++) {
            float alv0 = al[h * 32 + col], alv1 = al[h * 32 + 16 + col];
            float arv0 = ar[h * 32 + col], arv1 = ar[h * 32 + 16 + col];
            float pl[4], pr[4];
#pragma unroll
            for (int r = 0; r < 4; r++) {
                pl[r] = acc[rt][2 * h][r] * alv0 + acc[rt][2 * h + 1][r] * alv1;
                pr[r] = acc[rt][2 * h][r] * arv0 + acc[rt][2 * h + 1][r] * arv1;
            }
#pragma unroll
            for (int m = 1; m < 16; m <<= 1) {
#pragma unroll
                for (int r = 0; r < 4; r++) {
                    pl[r] += __shfl_xor(pl[r], m, 64);
                    pr[r] += __shfl_xor(pr[r], m, 64);
                }
            }
            if (col == h) {
#pragma unroll
                for (int r = 0; r < 4; r++) {
                    int row = r0 + rt * 16 + quad * 4 + r;
                    if (row < M) el[slotmap(row) * 4 + h] = pl[r] * LOG2E;
                }
            }
            if (col == 8 + h) {
#pragma unroll
                for (int r = 0; r < 4; r++) {
                    int row = r0 + rt * 16 + quad * 4 + r;
                    if (row < M) er[slotmap(row) * 4 + h] = pr[r] * LOG2E;
                }
            }
        }
    }
}

// C-store (interleaved row layout): pack row pairs with v_cvt_pk_bf16_f32
__device__ __forceinline__ void store_c_bf16(ushort_t* __restrict__ Cb,
                                             const float4v acc[2][8],
                                             int r0, int quad, int col, int M) {
#pragma unroll
    for (int rt = 0; rt < 2; rt++)
#pragma unroll
        for (int nt = 0; nt < 8; nt++) {
            int rb = r0 + rt * 16 + quad * 4;
            int c = nt * 16 + col;
            uint_t p01 = cvt_pk_bf16(acc[rt][nt][0], acc[rt][nt][1]);
            uint_t p23 = cvt_pk_bf16(acc[rt][nt][2], acc[rt][nt][3]);
            if (rb + 0 < M) Cb[(size_t)slotmap(rb + 0) * 128 + c] = (ushort_t)p01;
            if (rb + 1 < M) Cb[(size_t)slotmap(rb + 1) * 128 + c] = (ushort_t)(p01 >> 16);
            if (rb + 2 < M) Cb[(size_t)slotmap(rb + 2) * 128 + c] = (ushort_t)p23;
            if (rb + 3 < M) Cb[(size_t)slotmap(rb + 3) * 128 + c] = (ushort_t)(p23 >> 16);
        }
}

// ---------------- MFMA GEMM (fp32 A, layer 1) + fused el/er ----------------
__global__ __launch_bounds__(256) void gemm_mfma32(const float* __restrict__ A0,
                                                   const float* __restrict__ A1,
                                                   const ushort_t* __restrict__ WbT,
                                                   const float* __restrict__ al,
                                                   const float* __restrict__ ar,
                                                   ushort_t* __restrict__ Cb,
                                                   float* __restrict__ el,
                                                   float* __restrict__ er, int M) {
    __shared__ ushort_t Bs[128][136];
    int tid = threadIdx.x;
    for (int i = tid; i < 128 * 16; i += 256) {
        int n = i >> 4;
        int kc = (i & 15) << 3;
        *(short8*)&Bs[n][kc] = *(const short8*)&WbT[n * 128 + kc];
    }
    __syncthreads();
    int wid = tid >> 6, lane = tid & 63;
    int r0 = blockIdx.x * 128 + wid * 32;
    int col = lane & 15, quad = lane >> 4;
    float4v acc[2][8];
#pragma unroll
    for (int rt = 0; rt < 2; rt++)
#pragma unroll
        for (int t = 0; t < 8; t++) acc[rt][t] = (float4v){0.f, 0.f, 0.f, 0.f};
    int ar_[2] = {r0 + col, r0 + 16 + col};
    const float* Ap[2];
#pragma unroll
    for (int rt = 0; rt < 2; rt++) {
        int a = ar_[rt];
        Ap[rt] = (a < M) ? ((a < GN) ? (A0 + (size_t)a * 128)
                                     : (A1 + (size_t)(a - GN) * 128)) : nullptr;
    }
#pragma unroll
    for (int ks = 0; ks < 4; ks++) {
        short8 af[2];
#pragma unroll
        for (int rt = 0; rt < 2; rt++) {
            af[rt] = (short8){};
            if (Ap[rt]) {
                float4 v0 = *(const float4*)&Ap[rt][ks * 32 + quad * 8];
                float4 v1 = *(const float4*)&Ap[rt][ks * 32 + quad * 8 + 4];
                union { short8 s; uint_t u[4]; } cv;
                cv.u[0] = cvt_pk_bf16(v0.x, v0.y);
                cv.u[1] = cvt_pk_bf16(v0.z, v0.w);
                cv.u[2] = cvt_pk_bf16(v1.x, v1.y);
                cv.u[3] = cvt_pk_bf16(v1.z, v1.w);
                af[rt] = cv.s;
            }
        }
#pragma unroll
        for (int nt = 0; nt < 8; nt++) {
            short8 bf = *(const short8*)&Bs[nt * 16 + col][ks * 32 + quad * 8];
            acc[0][nt] = __builtin_amdgcn_mfma_f32_16x16x32_bf16(af[0], bf, acc[0][nt], 0, 0, 0);
            acc[1][nt] = __builtin_amdgcn_mfma_f32_16x16x32_bf16(af[1], bf, acc[1][nt], 0, 0, 0);
        }
    }
    store_c_bf16(Cb, acc, r0, quad, col, M);
    lr_epilogue(acc, al, ar, el, er, r0, quad, col, M);
}

// ---------------- MFMA GEMM (bf16 A interleaved, layer 2) + fused el/er ----------------
__global__ __launch_bounds__(256) void gemm_mfma(const ushort_t* __restrict__ A,
                                                 const ushort_t* __restrict__ WbT,
                                                 const float* __restrict__ al,
                                                 const float* __restrict__ ar,
                                                 ushort_t* __restrict__ Cb,
                                                 float* __restrict__ el,
                                                 float* __restrict__ er, int M) {
    __shared__ ushort_t Bs[128][136];
    int tid = threadIdx.x;
    for (int i = tid; i < 128 * 16; i += 256) {
        int n = i >> 4;
        int kc = (i & 15) << 3;
        *(short8*)&Bs[n][kc] = *(const short8*)&WbT[n * 128 + kc];
    }
    __syncthreads();
    int wid = tid >> 6, lane = tid & 63;
    int r0 = blockIdx.x * 128 + wid * 32;
    int col = lane & 15, quad = lane >> 4;
    float4v acc[2][8];
#pragma unroll
    for (int rt = 0; rt < 2; rt++)
#pragma unroll
        for (int t = 0; t < 8; t++) acc[rt][t] = (float4v){0.f, 0.f, 0.f, 0.f};
    int ar_[2] = {r0 + col, r0 + 16 + col};
    const ushort_t* Ap[2];
#pragma unroll
    for (int rt = 0; rt < 2; rt++) {
        int a = ar_[rt];
        Ap[rt] = (a < M) ? (A + (size_t)slotmap(a) * 128) : nullptr;
    }
#pragma unroll
    for (int ks = 0; ks < 4; ks++) {
        short8 af[2];
#pragma unroll
        for (int rt = 0; rt < 2; rt++) {
            af[rt] = (short8){};
            if (Ap[rt]) af[rt] = *(const short8*)&Ap[rt][ks * 32 + quad * 8];
        }
#pragma unroll
        for (int nt = 0; nt < 8; nt++) {
            short8 bf = *(const short8*)&Bs[nt * 16 + col][ks * 32 + quad * 8];
            acc[0][nt] = __builtin_amdgcn_mfma_f32_16x16x32_bf16(af[0], bf, acc[0][nt], 0, 0, 0);
            acc[1][nt] = __builtin_amdgcn_mfma_f32_16x16x32_bf16(af[1], bf, acc[1][nt], 0, 0, 0);
        }
    }
    store_c_bf16(Cb, acc, r0, quad, col, M);
    lr_epilogue(acc, al, ar, el, er, r0, quad, col, M);
}

// ---- shared agg gather core (interleaved layout) ----
// One wave per node; lanes 0-31 path0, 32-63 path1; lane q owns dims 4q..4q+3.
// All edges processed as ceil(deg/8) MASKED 8-edge blocks: clamped uniform csr
// indices, invalid lanes get weight exp2(-1e38)=0 (exact). No serial tail.
// Software pipeline prefetches next block's csr indices AND its el value.
__device__ __forceinline__ void agg_core(
    const ushort_t* __restrict__ featb, const float* __restrict__ el, float ern,
    const int* __restrict__ csr_src, int base, int deg, uint_t ebase, uint_t fofs,
    int lane, float& v0, float& v1, float& v2, float& v3) {
    if (deg <= 0) { v0 = v1 = v2 = v3 = 0.f; return; }
    float a0 = 0.f, a1 = 0.f, a2 = 0.f, a3 = 0.f, ss = 0.f;
    int lk = lane & 7;
    int nblk = (deg + 7) >> 3;
    int jb = base;
    // block 0 indices (clamped, wave-uniform -> scalar loads)
    int r1 = deg - 1;
    int s0 = csr_src[jb];
    int s1 = csr_src[jb + min(1, r1)];
    int s2 = csr_src[jb + min(2, r1)];
    int s3 = csr_src[jb + min(3, r1)];
    int s4 = csr_src[jb + min(4, r1)];
    int s5 = csr_src[jb + min(5, r1)];
    int s6 = csr_src[jb + min(6, r1)];
    int s7 = csr_src[jb + min(7, r1)];
    int sown = csr_src[jb + min(lk, r1)];
    float eown = el[ebase + (uint_t)sown * 8u];
    int b = 0;
    for (;;) {
        int rem = deg - (b << 3);
        // feature gathers: one contiguous 512B region per edge (both paths)
        const ushort_t* p0 = featb + (uint_t)s0 * 256u;
        const ushort_t* p1 = featb + (uint_t)s1 * 256u;
        const ushort_t* p2 = featb + (uint_t)s2 * 256u;
        const ushort_t* p3 = featb + (uint_t)s3 * 256u;
        const ushort_t* p4 = featb + (uint_t)s4 * 256u;
        const ushort_t* p5 = featb + (uint_t)s5 * 256u;
        const ushort_t* p6 = featb + (uint_t)s6 * 256u;
        const ushort_t* p7 = featb + (uint_t)s7 * 256u;
        uint2 f0 = *(const uint2*)&p0[fofs];
        uint2 f1 = *(const uint2*)&p1[fofs];
        uint2 f2 = *(const uint2*)&p2[fofs];
        uint2 f3 = *(const uint2*)&p3[fofs];
        uint2 f4 = *(const uint2*)&p4[fofs];
        uint2 f5 = *(const uint2*)&p5[fofs];
        uint2 f6 = *(const uint2*)&p6[fofs];
        uint2 f7 = *(const uint2*)&p7[fofs];
        // prefetch next block (indices + el) while gathers are in flight
        bool more = (b + 1) < nblk;
        int t0 = 0, t1 = 0, t2 = 0, t3 = 0, t4 = 0, t5 = 0, t6 = 0, t7 = 0, town = 0;
        float eon = 0.f;
        if (more) {
            int nj = jb + 8;
            int r2 = rem - 9;           // (next rem) - 1
            t0 = csr_src[nj];
            t1 = csr_src[nj + min(1, r2)];
            t2 = csr_src[nj + min(2, r2)];
            t3 = csr_src[nj + min(3, r2)];
            t4 = csr_src[nj + min(4, r2)];
            t5 = csr_src[nj + min(5, r2)];
            t6 = csr_src[nj + min(6, r2)];
            t7 = csr_src[nj + min(7, r2)];
            town = csr_src[nj + min(lk, r2)];
            eon = el[ebase + (uint_t)town * 8u];
        }
        float e = (lk < rem) ? (eown + ern) : -1e38f;
        e = fmaxf(e, SLOPE * e);
        float wown = EXP2F(e);
        // broadcast the 8 weights across the 8-lane (head,half) group
        float w0 = SWZ_B(wown, 0x018);
        float w1 = SWZ_B(wown, 0x038);
        float w2 = SWZ_B(wown, 0x058);
        float w3 = SWZ_B(wown, 0x078);
        float w4 = SWZ_B(wown, 0x098);
        float w5 = SWZ_B(wown, 0x0B8);
        float w6 = SWZ_B(wown, 0x0D8);
        float w7 = SWZ_B(wown, 0x0F8);
        ss += ((w0 + w1) + (w2 + w3)) + ((w4 + w5) + (w6 + w7));
        a0 += w0 * bflo(f0.x) + w1 * bflo(f1.x) + w2 * bflo(f2.x) + w3 * bflo(f3.x) +
              w4 * bflo(f4.x) + w5 * bflo(f5.x) + w6 * bflo(f6.x) + w7 * bflo(f7.x);
        a1 += w0 * bfhi(f0.x) + w1 * bfhi(f1.x) + w2 * bfhi(f2.x) + w3 * bfhi(f3.x) +
              w4 * bfhi(f4.x) + w5 * bfhi(f5.x) + w6 * bfhi(f6.x) + w7 * bfhi(f7.x);
        a2 += w0 * bflo(f0.y) + w1 * bflo(f1.y) + w2 * bflo(f2.y) + w3 * bflo(f3.y) +
              w4 * bflo(f4.y) + w5 * bflo(f5.y) + w6 * bflo(f6.y) + w7 * bflo(f7.y);
        a3 += w0 * bfhi(f0.y) + w1 * bfhi(f1.y) + w2 * bfhi(f2.y) + w3 * bfhi(f3.y) +
              w4 * bfhi(f4.y) + w5 * bfhi(f5.y) + w6 * bfhi(f6.y) + w7 * bfhi(f7.y);
        if (!more) break;
        b++; jb += 8;
        s0 = t0; s1 = t1; s2 = t2; s3 = t3; s4 = t4; s5 = t5; s6 = t6; s7 = t7;
        sown = town; eown = eon;
    }
    float inv = 1.f / ss;
    v0 = a0 * inv; v1 = a1 * inv; v2 = a2 * inv; v3 = a3 * inv;
}

// ---------------- layer-1 aggregate: -> abuf (bf16, interleaved) ----------------
__global__ __launch_bounds__(512) void gat_agg_l1(
    const ushort_t* __restrict__ featb, const float* __restrict__ el,
    const float* __restrict__ er, const int* __restrict__ row_ptr,
    const int* __restrict__ csr_src, ushort_t* __restrict__ abuf) {
    int n = __builtin_amdgcn_readfirstlane(blockIdx.x * 8 + (threadIdx.x >> 6));
    if (n >= GN) return;
    int lane = threadIdx.x & 63;
    int half = lane >> 5;
    int q = lane & 31;
    int head = (lane >> 3) & 3, q4 = q << 2;
    uint_t ebase = (uint_t)(half * 4 + head);
    uint_t fofs = (uint_t)(half * 128 + q4);
    float ern = er[(uint_t)n * 8u + ebase];
    int base = row_ptr[n];
    int deg = row_ptr[n + 1] - base;
    float v0, v1, v2, v3;
    agg_core(featb, el, ern, csr_src, base, deg, ebase, fofs, lane, v0, v1, v2, v3);
    v0 = v0 > 0.f ? v0 : __expf(v0) - 1.f;
    v1 = v1 > 0.f ? v1 : __expf(v1) - 1.f;
    v2 = v2 > 0.f ? v2 : __expf(v2) - 1.f;
    v3 = v3 > 0.f ? v3 : __expf(v3) - 1.f;
    size_t idx = ((size_t)(2 * n + half)) * 128 + q4;
    uint2 o;
    o.x = cvt_pk_bf16(v0, v1);
    o.y = cvt_pk_bf16(v2, v3);
    *(uint2*)&abuf[idx] = o;
}

// ---------------- layer-2 aggregate + residual + ELU + mixup + h write ----------------
__global__ __launch_bounds__(512) void gat_agg_l2(
    const ushort_t* __restrict__ featb, const float* __restrict__ el,
    const float* __restrict__ er, const int* __restrict__ row_ptr,
    const int* __restrict__ csr_src, const ushort_t* __restrict__ resid,
    const float* __restrict__ lamb, float* __restrict__ outh) {
    int tid = threadIdx.x;
    int n = __builtin_amdgcn_readfirstlane(blockIdx.x * 8 + (tid >> 6));
    if (n >= GN) return;
    int lane = tid & 63;
    int half = lane >> 5;
    int q = lane & 31;
    int head = (lane >> 3) & 3, q4 = q << 2;
    uint_t ebase = (uint_t)(half * 4 + head);
    uint_t fofs = (uint_t)(half * 128 + q4);
    float ern = er[(uint_t)n * 8u + ebase];
    int base = row_ptr[n];
    int deg = row_ptr[n + 1] - base;
    float v0, v1, v2, v3;
    agg_core(featb, el, ern, csr_src, base, deg, ebase, fofs, lane, v0, v1, v2, v3);
    // residual (bf16, interleaved) + ELU
    size_t idx = ((size_t)(2 * n + half)) * 128 + q4;
    ushort4 r = *(const ushort4*)&resid[idx];
    v0 += bfu(r.x); v1 += bfu(r.y); v2 += bfu(r.z); v3 += bfu(r.w);
    v0 = v0 > 0.f ? v0 : __expf(v0) - 1.f;
    v1 = v1 > 0.f ? v1 : __expf(v1) - 1.f;
    v2 = v2 > 0.f ? v2 : __expf(v2) - 1.f;
    v3 = v3 > 0.f ? v3 : __expf(v3) - 1.f;
    // mixup across halves (partner lane = lane ^ 32)
    float p0 = __shfl_xor(v0, 32, 64);
    float p1 = __shfl_xor(v1, 32, 64);
    float p2 = __shfl_xor(v2, 32, 64);
    float p3 = __shfl_xor(v3, 32, 64);
    float lam = lamb[0];
    if (half == 0) {
        float m0 = lam * v0 + (1.f - lam) * p0;
        float m1 = lam * v1 + (1.f - lam) * p1;
        float m2 = lam * v2 + (1.f - lam) * p2;
        float m3 = lam * v3 + (1.f - lam) * p3;
        *(float4*)&outh[(size_t)n * 128 + q4] = make_float4(m0, m1, m2, m3);
    }
}

// ---------------- logits: H[N,128] (f32) x Wout[128,40] via 3-product bf16-split MFMA
__global__ __launch_bounds__(256) void k_logits(const float* __restrict__ Hf,
                                                const ushort_t* __restrict__ Wb,
                                                const float* __restrict__ bout,
                                                float* __restrict__ outlog) {
    __shared__ ushort_t Bh[48][136];
    __shared__ ushort_t Bl[48][136];
    int tid = threadIdx.x;
    for (int i = tid; i < 48 * 16; i += 256) {
        int n = i >> 4;
        int kc = (i & 15) << 3;
        *(short8*)&Bh[n][kc] = *(const short8*)&Wb[n * 128 + kc];
        *(short8*)&Bl[n][kc] = *(const short8*)&Wb[48 * 128 + n * 128 + kc];
    }
    __syncthreads();
    int wid = tid >> 6, lane = tid & 63;
    int r0 = blockIdx.x * 128 + wid * 32;
    int col = lane & 15, quad = lane >> 4;
    float4v acc[2][3];
#pragma unroll
    for (int rt = 0; rt < 2; rt++)
#pragma unroll
        for (int nt = 0; nt < 3; nt++) acc[rt][nt] = (float4v){0.f, 0.f, 0.f, 0.f};
    int ar_[2] = {r0 + col, r0 + 16 + col};
#pragma unroll
    for (int ks = 0; ks < 4; ks++) {
        short8 ah[2], alo[2];
#pragma unroll
        for (int rt = 0; rt < 2; rt++) {
            ah[rt] = (short8){};
            alo[rt] = (short8){};
            if (ar_[rt] < GN) {
                const float* p = Hf + (size_t)ar_[rt] * 128 + ks * 32 + quad * 8;
                float4 x = *(const float4*)p;
                float4 y = *(const float4*)(p + 4);
                union { short8 s; uint_t u[4]; } ch, cl;
                ch.u[0] = cvt_pk_bf16(x.x, x.y);
                ch.u[1] = cvt_pk_bf16(x.z, x.w);
                ch.u[2] = cvt_pk_bf16(y.x, y.y);
                ch.u[3] = cvt_pk_bf16(y.z, y.w);
                cl.u[0] = cvt_pk_bf16(x.x - bflo(ch.u[0]), x.y - bfhi(ch.u[0]));
                cl.u[1] = cvt_pk_bf16(x.z - bflo(ch.u[1]), x.w - bfhi(ch.u[1]));
                cl.u[2] = cvt_pk_bf16(y.x - bflo(ch.u[2]), y.y - bfhi(ch.u[2]));
                cl.u[3] = cvt_pk_bf16(y.z - bflo(ch.u[3]), y.w - bfhi(ch.u[3]));
                ah[rt] = ch.s;
                alo[rt] = cl.s;
            }
        }
#pragma unroll
        for (int nt = 0; nt < 3; nt++) {
            short8 bh = *(const short8*)&Bh[nt * 16 + col][ks * 32 + quad * 8];
            short8 bl = *(const short8*)&Bl[nt * 16 + col][ks * 32 + quad * 8];
#pragma unroll
            for (int rt = 0; rt < 2; rt++) {
                acc[rt][nt] = __builtin_amdgcn_mfma_f32_16x16x32_bf16(ah[rt], bh, acc[rt][nt], 0, 0, 0);
                acc[rt][nt] = __builtin_amdgcn_mfma_f32_16x16x32_bf16(alo[rt], bh, acc[rt][nt], 0, 0, 0);
                acc[rt][nt] = __builtin_amdgcn_mfma_f32_16x16x32_bf16(ah[rt], bl, acc[rt][nt], 0, 0, 0);
            }
        }
    }
#pragma unroll
    for (int nt = 0; nt < 3; nt++) {
        int c = nt * 16 + col;
        if (c < 40) {
            float bv = bout[c];
#pragma unroll
            for (int rt = 0; rt < 2; rt++)
#pragma unroll
                for (int r = 0; r < 4; r++) {
                    int row = r0 + rt * 16 + quad * 4 + r;
                    if (row < GN) outlog[(size_t)row * 40 + c] = acc[rt][nt][r] + bv;
                }
        }
    }
}

extern "C" void kernel_launch(void* const* d_in, const int* in_sizes, int n_in,
                              void* d_out, int out_size, void* d_ws, size_t ws_size,
                              hipStream_t stream) {
    const float* inputs = (const float*)d_in[0];
    const float* target = (const float*)d_in[1];
    const float* lamb   = (const float*)d_in[2];
    const float* W0     = (const float*)d_in[3];
    const float* al0    = (const float*)d_in[4];
    const float* ar0    = (const float*)d_in[5];
    const float* W1     = (const float*)d_in[6];
    const float* al1    = (const float*)d_in[7];
    const float* ar1    = (const float*)d_in[8];
    const float* Wout   = (const float*)d_in[9];
    const float* bout   = (const float*)d_in[10];
    const int*   src    = (const int*)d_in[11];
    const int*   dst    = (const int*)d_in[12];

    float* out = (float*)d_out;
    float* outh = out;                          // [N,128]
    float* outlog = out + (size_t)GN * 128;     // [N,40]

    const int NP = 2 * GN;
    // workspace layout (featb/abuf/el/er are path-INTERLEAVED: slot = 2n+half)
    ushort_t* featb = (ushort_t*)d_ws;                    // [2N,128] bf16
    ushort_t* abuf  = featb + (size_t)NP * 128;           // [2N,128] bf16 (layer1 out / resid)
    float* el = (float*)(abuf + (size_t)NP * 128);        // [2N,4]  (pre-scaled by LOG2E)
    float* er = el + (size_t)NP * GH;                     // [2N,4]  (pre-scaled by LOG2E)
    ushort_t* wbt = (ushort_t*)(er + (size_t)NP * GH);    // [2][128][128] bf16
    int* row_ptr  = (int*)(wbt + 2 * 128 * 128);          // N+1
    int* wpos     = row_ptr + (GN + 1);                   // N
    int* csr_src  = wpos + GN;                            // E (+pad)
    int* partials = csr_src + GE + 16;                    // 256
    ushort_t* woutb = (ushort_t*)(partials + 256);        // [2][48][128] bf16 hi/lo

    const int nb = (GN + 255) / 256;
    const int eb = (GE + 255) / 256;
    const int gblocks = (NP + 127) / 128;
    const int aggblocks = (GN + 7) / 8;
    const int lblocks = (GN + 127) / 128;

    // ---- CSR build ----
    hipMemsetAsync(wpos, 0, GN * sizeof(int), stream);
    k_hist<<<eb, 256, 0, stream>>>(dst, wpos, GE);
    k_scan1<<<nb, 256, 0, stream>>>(wpos, row_ptr, partials, GN);
    k_scan2<<<1, 256, 0, stream>>>(partials, nb);
    k_scan3<<<nb, 256, 0, stream>>>(row_ptr, wpos, partials, GN, GE);
    k_fill<<<eb, 256, 0, stream>>>(src, dst, wpos, csr_src, GE);

    // ---- weights convert ----
    k_cvt_w<<<128, 256, 0, stream>>>(W0, W1, wbt);
    k_cvt_wout<<<24, 256, 0, stream>>>(Wout, woutb);

    // ---- layer 1 (GEMM fuses el/er; agg fuses softmax-weight + ELU) ----
    gemm_mfma32<<<gblocks, 256, 0, stream>>>(inputs, target, wbt, al0, ar0,
                                             featb, el, er, NP);
    gat_agg_l1<<<aggblocks, 512, 0, stream>>>(featb, el, er, row_ptr, csr_src, abuf);

    // ---- layer 2 (agg fuses residual + ELU + mixup + h-write) ----
    gemm_mfma<<<gblocks, 256, 0, stream>>>(abuf, wbt + 128 * 128, al1, ar1,
                                           featb, el, er, NP);
    gat_agg_l2<<<aggblocks, 512, 0, stream>>>(featb, el, er, row_ptr, csr_src,
                                              abuf, lamb, outh);

    // ---- logits from outh (fp32-accurate 3-product bf16 split MFMA) ----
    k_logits<<<lblocks, 256, 0, stream>>>(outh, woutb, bout, outlog);
}

// Round 4
// 396.496 us; speedup vs baseline: 1.1134x; 1.0260x over previous
//
#include <hip/hip_runtime.h>
#include <hip/hip_bf16.h>
#include <cstddef>

#define GN 50000
#define GE 800000
#define GH 4
#define GD 32
#define SLOPE 0.2f
#define LOG2E 1.4426950408889634f

typedef unsigned short ushort_t;
typedef unsigned int uint_t;
using short8 = __attribute__((ext_vector_type(8))) short;
using float4v = __attribute__((ext_vector_type(4))) float;

__device__ __forceinline__ ushort_t f2bf(float f) {
    union { float f; uint_t u; } v; v.f = f;
    uint_t r = v.u + 0x7fff + ((v.u >> 16) & 1);   // RNE
    return (ushort_t)(r >> 16);
}
__device__ __forceinline__ float bflo(uint_t u) { return __uint_as_float(u << 16); }
__device__ __forceinline__ float bfhi(uint_t u) { return __uint_as_float(u & 0xffff0000u); }
__device__ __forceinline__ float bfu(ushort_t u) { return __uint_as_float((uint_t)u << 16); }

// v_cvt_pk_bf16_f32: D[15:0]=bf16(lo), D[31:16]=bf16(hi), RNE — same rounding as f2bf
__device__ __forceinline__ uint_t cvt_pk_bf16(float lo, float hi) {
    uint_t r;
    asm("v_cvt_pk_bf16_f32 %0, %1, %2" : "=v"(r) : "v"(lo), "v"(hi));
    return r;
}

#if __has_builtin(__builtin_amdgcn_exp2f)
#define EXP2F(x) __builtin_amdgcn_exp2f(x)
#else
#define EXP2F(x) exp2f(x)
#endif

// path-interleaved row slot: storage row a (0..2N) -> slot (path0/path1 interleaved)
__device__ __forceinline__ int slotmap(int a) {
    return (a < GN) ? (a << 1) : (((a - GN) << 1) | 1);
}

// ---------------- CSR build ----------------
__global__ void k_hist(const int* __restrict__ dst, int* __restrict__ deg, int E) {
    int i = blockIdx.x * 256 + threadIdx.x;
    if (i < E) atomicAdd(&deg[dst[i]], 1);
}

__global__ void k_scan1(const int* __restrict__ deg, int* __restrict__ row_ptr,
                        int* __restrict__ partials, int n) {
    __shared__ int s[256];
    int t = threadIdx.x;
    int i = blockIdx.x * 256 + t;
    int v = (i < n) ? deg[i] : 0;
    s[t] = v;
    __syncthreads();
    for (int off = 1; off < 256; off <<= 1) {
        int add = (t >= off) ? s[t - off] : 0;
        __syncthreads();
        s[t] += add;
        __syncthreads();
    }
    if (i < n) row_ptr[i] = s[t] - v;
    if (t == 255) partials[blockIdx.x] = s[255];
}

__global__ void k_scan2(int* __restrict__ partials, int nb) {
    __shared__ int s[256];
    int t = threadIdx.x;
    int v = (t < nb) ? partials[t] : 0;
    s[t] = v;
    __syncthreads();
    for (int off = 1; off < 256; off <<= 1) {
        int add = (t >= off) ? s[t - off] : 0;
        __syncthreads();
        s[t] += add;
        __syncthreads();
    }
    if (t < nb) partials[t] = s[t] - v;
}

__global__ void k_scan3(int* __restrict__ row_ptr, int* __restrict__ wpos,
                        const int* __restrict__ partials, int n, int E) {
    int i = blockIdx.x * 256 + threadIdx.x;
    if (i < n) {
        int rp = row_ptr[i] + partials[i >> 8];
        row_ptr[i] = rp;
        wpos[i] = rp;
        if (i == 0) row_ptr[n] = E;
    }
}

__global__ void k_fill(const int* __restrict__ src, const int* __restrict__ dst,
                       int* __restrict__ wpos, int* __restrict__ csr_src, int E) {
    int i = blockIdx.x * 256 + threadIdx.x;
    if (i < E) {
        int p = atomicAdd(&wpos[dst[i]], 1);
        csr_src[p] = src[i];
    }
}

// ---------------- weight transpose+convert (merged) ----------------
__global__ void k_cvt_all(const float* __restrict__ W0, const float* __restrict__ W1,
                          const float* __restrict__ Wout,
                          ushort_t* __restrict__ wbt, ushort_t* __restrict__ woutb) {
    int t = blockIdx.x * 256 + threadIdx.x;
    if (t < 32768) {
        int m = t >> 14;
        int o = t & 16383;
        int n = o >> 7, k = o & 127;
        const float* W = m ? W1 : W0;
        wbt[t] = f2bf(W[k * 128 + n]);
    } else {
        int u = t - 32768;            // 0..6143
        if (u < 48 * 128) {
            int n = u >> 7, k = u & 127;
            float w = (n < 40) ? Wout[k * 40 + n] : 0.f;
            ushort_t h = f2bf(w);
            woutb[u] = h;
            woutb[48 * 128 + u] = f2bf(w - bfu(h));
        }
    }
}

// ---- fused er epilogue over MFMA accumulator (interleaved er layout) ----
// stores er pre-scaled by LOG2E so agg can use raw v_exp_f32 (exp2).
// (el is now computed in-register inside the agg kernels from bf16 features.)
__device__ __forceinline__ void lr_epilogue(const float4v acc[2][8],
                                            const float* __restrict__ ar,
                                            float* __restrict__ er,
                                            int r0, int quad, int col, int M) {
#pragma unroll
    for (int rt = 0; rt < 2; rt++) {
#pragma unroll
        for (int h = 0; h < 4; h++) {
            float arv0 = ar[h * 32 + col], arv1 = ar[h * 32 + 16 + col];
            float pr[4];
#pragma unroll
            for (int r = 0; r < 4; r++)
                pr[r] = acc[rt][2 * h][r] * arv0 + acc[rt][2 * h + 1][r] * arv1;
#pragma unroll
            for (int m = 1; m < 16; m <<= 1) {
#pragma unroll
                for (int r = 0; r < 4; r++) pr[r] += __shfl_xor(pr[r], m, 64);
            }
            if (col == 8 + h) {
#pragma unroll
                for (int r = 0; r < 4; r++) {
                    int row = r0 + rt * 16 + quad * 4 + r;
                    if (row < M) er[slotmap(row) * 4 + h] = pr[r] * LOG2E;
                }
            }
        }
    }
}

// C-store (interleaved row layout): pack row pairs with v_cvt_pk_bf16_f32
__device__ __forceinline__ void store_c_bf16(ushort_t* __restrict__ Cb,
                                             const float4v acc[2][8],
                                             int r0, int quad, int col, int M) {
#pragma unroll
    for (int rt = 0; rt < 2; rt++)
#pragma unroll
        for (int nt = 0; nt < 8; nt++) {
            int rb = r0 + rt * 16 + quad * 4;
            int c = nt * 16 + col;
            uint_t p01 = cvt_pk_bf16(acc[rt][nt][0], acc[rt][nt][1]);
            uint_t p23 = cvt_pk_bf16(acc[rt][nt][2], acc[rt][nt][3]);
            if (rb + 0 < M) Cb[(size_t)slotmap(rb + 0) * 128 + c] = (ushort_t)p01;
            if (rb + 1 < M) Cb[(size_t)slotmap(rb + 1) * 128 + c] = (ushort_t)(p01 >> 16);
            if (rb + 2 < M) Cb[(size_t)slotmap(rb + 2) * 128 + c] = (ushort_t)p23;
            if (rb + 3 < M) Cb[(size_t)slotmap(rb + 3) * 128 + c] = (ushort_t)(p23 >> 16);
        }
}

// ---------------- MFMA GEMM (fp32 A, layer 1) + fused er ----------------
__global__ __launch_bounds__(256) void gemm_mfma32(const float* __restrict__ A0,
                                                   const float* __restrict__ A1,
                                                   const ushort_t* __restrict__ WbT,
                                                   const float* __restrict__ ar,
                                                   ushort_t* __restrict__ Cb,
                                                   float* __restrict__ er, int M) {
    __shared__ ushort_t Bs[128][136];
    int tid = threadIdx.x;
    for (int i = tid; i < 128 * 16; i += 256) {
        int n = i >> 4;
        int kc = (i & 15) << 3;
        *(short8*)&Bs[n][kc] = *(const short8*)&WbT[n * 128 + kc];
    }
    __syncthreads();
    int wid = tid >> 6, lane = tid & 63;
    int r0 = blockIdx.x * 128 + wid * 32;
    int col = lane & 15, quad = lane >> 4;
    float4v acc[2][8];
#pragma unroll
    for (int rt = 0; rt < 2; rt++)
#pragma unroll
        for (int t = 0; t < 8; t++) acc[rt][t] = (float4v){0.f, 0.f, 0.f, 0.f};
    int ar_[2] = {r0 + col, r0 + 16 + col};
    const float* Ap[2];
#pragma unroll
    for (int rt = 0; rt < 2; rt++) {
        int a = ar_[rt];
        Ap[rt] = (a < M) ? ((a < GN) ? (A0 + (size_t)a * 128)
                                     : (A1 + (size_t)(a - GN) * 128)) : nullptr;
    }
#pragma unroll
    for (int ks = 0; ks < 4; ks++) {
        short8 af[2];
#pragma unroll
        for (int rt = 0; rt < 2; rt++) {
            af[rt] = (short8){};
            if (Ap[rt]) {
                float4 v0 = *(const float4*)&Ap[rt][ks * 32 + quad * 8];
                float4 v1 = *(const float4*)&Ap[rt][ks * 32 + quad * 8 + 4];
                union { short8 s; uint_t u[4]; } cv;
                cv.u[0] = cvt_pk_bf16(v0.x, v0.y);
                cv.u[1] = cvt_pk_bf16(v0.z, v0.w);
                cv.u[2] = cvt_pk_bf16(v1.x, v1.y);
                cv.u[3] = cvt_pk_bf16(v1.z, v1.w);
                af[rt] = cv.s;
            }
        }
#pragma unroll
        for (int nt = 0; nt < 8; nt++) {
            short8 bf = *(const short8*)&Bs[nt * 16 + col][ks * 32 + quad * 8];
            acc[0][nt] = __builtin_amdgcn_mfma_f32_16x16x32_bf16(af[0], bf, acc[0][nt], 0, 0, 0);
            acc[1][nt] = __builtin_amdgcn_mfma_f32_16x16x32_bf16(af[1], bf, acc[1][nt], 0, 0, 0);
        }
    }
    store_c_bf16(Cb, acc, r0, quad, col, M);
    lr_epilogue(acc, ar, er, r0, quad, col, M);
}

// ---------------- MFMA GEMM (bf16 A interleaved, layer 2) + fused er ----------------
__global__ __launch_bounds__(256) void gemm_mfma(const ushort_t* __restrict__ A,
                                                 const ushort_t* __restrict__ WbT,
                                                 const float* __restrict__ ar,
                                                 ushort_t* __restrict__ Cb,
                                                 float* __restrict__ er, int M) {
    __shared__ ushort_t Bs[128][136];
    int tid = threadIdx.x;
    for (int i = tid; i < 128 * 16; i += 256) {
        int n = i >> 4;
        int kc = (i & 15) << 3;
        *(short8*)&Bs[n][kc] = *(const short8*)&WbT[n * 128 + kc];
    }
    __syncthreads();
    int wid = tid >> 6, lane = tid & 63;
    int r0 = blockIdx.x * 128 + wid * 32;
    int col = lane & 15, quad = lane >> 4;
    float4v acc[2][8];
#pragma unroll
    for (int rt = 0; rt < 2; rt++)
#pragma unroll
        for (int t = 0; t < 8; t++) acc[rt][t] = (float4v){0.f, 0.f, 0.f, 0.f};
    int ar_[2] = {r0 + col, r0 + 16 + col};
    const ushort_t* Ap[2];
#pragma unroll
    for (int rt = 0; rt < 2; rt++) {
        int a = ar_[rt];
        Ap[rt] = (a < M) ? (A + (size_t)slotmap(a) * 128) : nullptr;
    }
#pragma unroll
    for (int ks = 0; ks < 4; ks++) {
        short8 af[2];
#pragma unroll
        for (int rt = 0; rt < 2; rt++) {
            af[rt] = (short8){};
            if (Ap[rt]) af[rt] = *(const short8*)&Ap[rt][ks * 32 + quad * 8];
        }
#pragma unroll
        for (int nt = 0; nt < 8; nt++) {
            short8 bf = *(const short8*)&Bs[nt * 16 + col][ks * 32 + quad * 8];
            acc[0][nt] = __builtin_amdgcn_mfma_f32_16x16x32_bf16(af[0], bf, acc[0][nt], 0, 0, 0);
            acc[1][nt] = __builtin_amdgcn_mfma_f32_16x16x32_bf16(af[1], bf, acc[1][nt], 0, 0, 0);
        }
    }
    store_c_bf16(Cb, acc, r0, quad, col, M);
    lr_epilogue(acc, ar, er, r0, quad, col, M);
}

// ---- shared agg gather core (interleaved layout, in-register el) ----
// One wave per node; lanes 0-31 path0, 32-63 path1; lane q owns dims 4q..4q+3.
// 16-edge masked blocks: clamped wave-uniform csr indices (SGPRs, scalar loads);
// invalid edges get weight 0 via uniform (k<rem) predicate. el is computed
// IN-REGISTER from the gathered feature chunks: dot4 with this lane's al chunk,
// 3-step shfl_xor reduce within the 8-lane (head,half) group. No el gather,
// no el buffer, no ds_swizzle broadcasts. alv/ern are pre-scaled by LOG2E.
__device__ __forceinline__ void agg_core(
    const ushort_t* __restrict__ featb, float4 alv, float ern,
    const int* __restrict__ csr_src, int base, int deg, uint_t fofs,
    float& v0, float& v1, float& v2, float& v3) {
    if (deg <= 0) { v0 = v1 = v2 = v3 = 0.f; return; }
    float a0 = 0.f, a1 = 0.f, a2 = 0.f, a3 = 0.f, ss = 0.f;
    int nblk = (deg + 15) >> 4;
    int jb = base;
    int r1 = deg - 1;
    int s[16], t[16];
#pragma unroll
    for (int k = 0; k < 16; k++) s[k] = csr_src[jb + min(k, r1)];
    int b = 0;
    for (;;) {
        int rem = deg - (b << 4);
        uint2 f[16];
#pragma unroll
        for (int k = 0; k < 16; k++)
            f[k] = *(const uint2*)&featb[(uint_t)s[k] * 256u + fofs];
        // prefetch next block's indices while gathers are in flight
        bool more = (b + 1) < nblk;
        if (more) {
            int nj = jb + 16;
            int r2 = rem - 17;
#pragma unroll
            for (int k = 0; k < 16; k++) t[k] = csr_src[nj + min(k, r2)];
        }
#pragma unroll
        for (int k = 0; k < 16; k++) {
            float x0 = bflo(f[k].x), x1 = bfhi(f[k].x);
            float x2 = bflo(f[k].y), x3 = bfhi(f[k].y);
            // in-register el: dot4 + 8-lane group butterfly reduce
            float d = x0 * alv.x + x1 * alv.y + x2 * alv.z + x3 * alv.w;
            d += __shfl_xor(d, 1, 64);
            d += __shfl_xor(d, 2, 64);
            d += __shfl_xor(d, 4, 64);
            float e = d + ern;
            e = fmaxf(e, SLOPE * e);   // leaky (scale-commutes with LOG2E)
            float w = (k < rem) ? EXP2F(e) : 0.f;
            ss += w;
            a0 += w * x0; a1 += w * x1; a2 += w * x2; a3 += w * x3;
        }
        if (!more) break;
        b++; jb += 16;
#pragma unroll
        for (int k = 0; k < 16; k++) s[k] = t[k];
    }
    float inv = 1.f / ss;
    v0 = a0 * inv; v1 = a1 * inv; v2 = a2 * inv; v3 = a3 * inv;
}

// ---------------- layer-1 aggregate: -> abuf (bf16, interleaved) ----------------
__global__ __launch_bounds__(512) void gat_agg_l1(
    const ushort_t* __restrict__ featb, const float* __restrict__ al,
    const float* __restrict__ er, const int* __restrict__ row_ptr,
    const int* __restrict__ csr_src, ushort_t* __restrict__ abuf) {
    int n = __builtin_amdgcn_readfirstlane(blockIdx.x * 8 + (threadIdx.x >> 6));
    if (n >= GN) return;
    int lane = threadIdx.x & 63;
    int half = lane >> 5;
    int q = lane & 31;
    int head = (lane >> 3) & 3, j8 = lane & 7, q4 = q << 2;
    float4 alv = *(const float4*)&al[head * 32 + j8 * 4];
    alv.x *= LOG2E; alv.y *= LOG2E; alv.z *= LOG2E; alv.w *= LOG2E;
    uint_t fofs = (uint_t)(half * 128 + q4);
    float ern = er[(uint_t)n * 8u + (uint_t)(half * 4 + head)];
    int base = row_ptr[n];
    int deg = row_ptr[n + 1] - base;
    float v0, v1, v2, v3;
    agg_core(featb, alv, ern, csr_src, base, deg, fofs, v0, v1, v2, v3);
    v0 = v0 > 0.f ? v0 : __expf(v0) - 1.f;
    v1 = v1 > 0.f ? v1 : __expf(v1) - 1.f;
    v2 = v2 > 0.f ? v2 : __expf(v2) - 1.f;
    v3 = v3 > 0.f ? v3 : __expf(v3) - 1.f;
    size_t idx = ((size_t)(2 * n + half)) * 128 + q4;
    uint2 o;
    o.x = cvt_pk_bf16(v0, v1);
    o.y = cvt_pk_bf16(v2, v3);
    *(uint2*)&abuf[idx] = o;
}

// ---------------- layer-2 aggregate + residual + ELU + mixup + h write ----------------
__global__ __launch_bounds__(512) void gat_agg_l2(
    const ushort_t* __restrict__ featb, const float* __restrict__ al,
    const float* __restrict__ er, const int* __restrict__ row_ptr,
    const int* __restrict__ csr_src, const ushort_t* __restrict__ resid,
    const float* __restrict__ lamb, float* __restrict__ outh) {
    int tid = threadIdx.x;
    int n = __builtin_amdgcn_readfirstlane(blockIdx.x * 8 + (tid >> 6));
    if (n >= GN) return;
    int lane = tid & 63;
    int half = lane >> 5;
    int q = lane & 31;
    int head = (lane >> 3) & 3, j8 = lane & 7, q4 = q << 2;
    float4 alv = *(const float4*)&al[head * 32 + j8 * 4];
    alv.x *= LOG2E; alv.y *= LOG2E; alv.z *= LOG2E; alv.w *= LOG2E;
    uint_t fofs = (uint_t)(half * 128 + q4);
    float ern = er[(uint_t)n * 8u + (uint_t)(half * 4 + head)];
    int base = row_ptr[n];
    int deg = row_ptr[n + 1] - base;
    float v0, v1, v2, v3;
    agg_core(featb, alv, ern, csr_src, base, deg, fofs, v0, v1, v2, v3);
    // residual (bf16, interleaved) + ELU
    size_t idx = ((size_t)(2 * n + half)) * 128 + q4;
    ushort4 r = *(const ushort4*)&resid[idx];
    v0 += bfu(r.x); v1 += bfu(r.y); v2 += bfu(r.z); v3 += bfu(r.w);
    v0 = v0 > 0.f ? v0 : __expf(v0) - 1.f;
    v1 = v1 > 0.f ? v1 : __expf(v1) - 1.f;
    v2 = v2 > 0.f ? v2 : __expf(v2) - 1.f;
    v3 = v3 > 0.f ? v3 : __expf(v3) - 1.f;
    // mixup across halves (partner lane = lane ^ 32)
    float p0 = __shfl_xor(v0, 32, 64);
    float p1 = __shfl_xor(v1, 32, 64);
    float p2 = __shfl_xor(v2, 32, 64);
    float p3 = __shfl_xor(v3, 32, 64);
    float lam = lamb[0];
    if (half == 0) {
        float m0 = lam * v0 + (1.f - lam) * p0;
        float m1 = lam * v1 + (1.f - lam) * p1;
        float m2 = lam * v2 + (1.f - lam) * p2;
        float m3 = lam * v3 + (1.f - lam) * p3;
        *(float4*)&outh[(size_t)n * 128 + q4] = make_float4(m0, m1, m2, m3);
    }
}

// ---------------- logits: H[N,128] (f32) x Wout[128,40] via 3-product bf16-split MFMA
__global__ __launch_bounds__(256) void k_logits(const float* __restrict__ Hf,
                                                const ushort_t* __restrict__ Wb,
                                                const float* __restrict__ bout,
                                                float* __restrict__ outlog) {
    __shared__ ushort_t Bh[48][136];
    __shared__ ushort_t Bl[48][136];
    int tid = threadIdx.x;
    for (int i = tid; i < 48 * 16; i += 256) {
        int n = i >> 4;
        int kc = (i & 15) << 3;
        *(short8*)&Bh[n][kc] = *(const short8*)&Wb[n * 128 + kc];
        *(short8*)&Bl[n][kc] = *(const short8*)&Wb[48 * 128 + n * 128 + kc];
    }
    __syncthreads();
    int wid = tid >> 6, lane = tid & 63;
    int r0 = blockIdx.x * 128 + wid * 32;
    int col = lane & 15, quad = lane >> 4;
    float4v acc[2][3];
#pragma unroll
    for (int rt = 0; rt < 2; rt++)
#pragma unroll
        for (int nt = 0; nt < 3; nt++) acc[rt][nt] = (float4v){0.f, 0.f, 0.f, 0.f};
    int ar_[2] = {r0 + col, r0 + 16 + col};
#pragma unroll
    for (int ks = 0; ks < 4; ks++) {
        short8 ah[2], alo[2];
#pragma unroll
        for (int rt = 0; rt < 2; rt++) {
            ah[rt] = (short8){};
            alo[rt] = (short8){};
            if (ar_[rt] < GN) {
                const float* p = Hf + (size_t)ar_[rt] * 128 + ks * 32 + quad * 8;
                float4 x = *(const float4*)p;
                float4 y = *(const float4*)(p + 4);
                union { short8 s; uint_t u[4]; } ch, cl;
                ch.u[0] = cvt_pk_bf16(x.x, x.y);
                ch.u[1] = cvt_pk_bf16(x.z, x.w);
                ch.u[2] = cvt_pk_bf16(y.x, y.y);
                ch.u[3] = cvt_pk_bf16(y.z, y.w);
                cl.u[0] = cvt_pk_bf16(x.x - bflo(ch.u[0]), x.y - bfhi(ch.u[0]));
                cl.u[1] = cvt_pk_bf16(x.z - bflo(ch.u[1]), x.w - bfhi(ch.u[1]));
                cl.u[2] = cvt_pk_bf16(y.x - bflo(ch.u[2]), y.y - bfhi(ch.u[2]));
                cl.u[3] = cvt_pk_bf16(y.z - bflo(ch.u[3]), y.w - bfhi(ch.u[3]));
                ah[rt] = ch.s;
                alo[rt] = cl.s;
            }
        }
#pragma unroll
        for (int nt = 0; nt < 3; nt++) {
            short8 bh = *(const short8*)&Bh[nt * 16 + col][ks * 32 + quad * 8];
            short8 bl = *(const short8*)&Bl[nt * 16 + col][ks * 32 + quad * 8];
#pragma unroll
            for (int rt = 0; rt < 2; rt++) {
                acc[rt][nt] = __builtin_amdgcn_mfma_f32_16x16x32_bf16(ah[rt], bh, acc[rt][nt], 0, 0, 0);
                acc[rt][nt] = __builtin_amdgcn_mfma_f32_16x16x32_bf16(alo[rt], bh, acc[rt][nt], 0, 0, 0);
                acc[rt][nt] = __builtin_amdgcn_mfma_f32_16x16x32_bf16(ah[rt], bl, acc[rt][nt], 0, 0, 0);
            }
        }
    }
#pragma unroll
    for (int nt = 0; nt < 3; nt++) {
        int c = nt * 16 + col;
        if (c < 40) {
            float bv = bout[c];
#pragma unroll
            for (int rt = 0; rt < 2; rt++)
#pragma unroll
                for (int r = 0; r < 4; r++) {
                    int row = r0 + rt * 16 + quad * 4 + r;
                    if (row < GN) outlog[(size_t)row * 40 + c] = acc[rt][nt][r] + bv;
                }
        }
    }
}

extern "C" void kernel_launch(void* const* d_in, const int* in_sizes, int n_in,
                              void* d_out, int out_size, void* d_ws, size_t ws_size,
                              hipStream_t stream) {
    const float* inputs = (const float*)d_in[0];
    const float* target = (const float*)d_in[1];
    const float* lamb   = (const float*)d_in[2];
    const float* W0     = (const float*)d_in[3];
    const float* al0    = (const float*)d_in[4];
    const float* ar0    = (const float*)d_in[5];
    const float* W1     = (const float*)d_in[6];
    const float* al1    = (const float*)d_in[7];
    const float* ar1    = (const float*)d_in[8];
    const float* Wout   = (const float*)d_in[9];
    const float* bout   = (const float*)d_in[10];
    const int*   src    = (const int*)d_in[11];
    const int*   dst    = (const int*)d_in[12];

    float* out = (float*)d_out;
    float* outh = out;                          // [N,128]
    float* outlog = out + (size_t)GN * 128;     // [N,40]

    const int NP = 2 * GN;
    // workspace layout (featb/abuf/er are path-INTERLEAVED: slot = 2n+half)
    ushort_t* featb = (ushort_t*)d_ws;                    // [2N,128] bf16
    ushort_t* abuf  = featb + (size_t)NP * 128;           // [2N,128] bf16 (layer1 out / resid)
    float* er = (float*)(abuf + (size_t)NP * 128);        // [2N,4]  (pre-scaled by LOG2E)
    ushort_t* wbt = (ushort_t*)(er + (size_t)NP * GH);    // [2][128][128] bf16
    int* row_ptr  = (int*)(wbt + 2 * 128 * 128);          // N+1
    int* wpos     = row_ptr + (GN + 1);                   // N
    int* csr_src  = wpos + GN;                            // E (+pad)
    int* partials = csr_src + GE + 16;                    // 256
    ushort_t* woutb = (ushort_t*)(partials + 256);        // [2][48][128] bf16 hi/lo

    const int nb = (GN + 255) / 256;
    const int eb = (GE + 255) / 256;
    const int gblocks = (NP + 127) / 128;
    const int aggblocks = (GN + 7) / 8;
    const int lblocks = (GN + 127) / 128;

    // ---- CSR build ----
    hipMemsetAsync(wpos, 0, GN * sizeof(int), stream);
    k_hist<<<eb, 256, 0, stream>>>(dst, wpos, GE);
    k_scan1<<<nb, 256, 0, stream>>>(wpos, row_ptr, partials, GN);
    k_scan2<<<1, 256, 0, stream>>>(partials, nb);
    k_scan3<<<nb, 256, 0, stream>>>(row_ptr, wpos, partials, GN, GE);
    k_fill<<<eb, 256, 0, stream>>>(src, dst, wpos, csr_src, GE);

    // ---- weights convert (merged) ----
    k_cvt_all<<<152, 256, 0, stream>>>(W0, W1, Wout, wbt, woutb);

    // ---- layer 1 (GEMM fuses er; agg computes el in-register + softmax + ELU) ----
    gemm_mfma32<<<gblocks, 256, 0, stream>>>(inputs, target, wbt, ar0,
                                             featb, er, NP);
    gat_agg_l1<<<aggblocks, 512, 0, stream>>>(featb, al0, er, row_ptr, csr_src, abuf);

    // ---- layer 2 (agg fuses residual + ELU + mixup + h-write) ----
    gemm_mfma<<<gblocks, 256, 0, stream>>>(abuf, wbt + 128 * 128, ar1,
                                           featb, er, NP);
    gat_agg_l2<<<aggblocks, 512, 0, stream>>>(featb, al1, er, row_ptr, csr_src,
                                              abuf, lamb, outh);

    // ---- logits from outh (fp32-accurate 3-product bf16 split MFMA) ----
    k_logits<<<lblocks, 256, 0, stream>>>(outh, woutb, bout, outlog);
}